// Round 10
// baseline (162.220 us; speedup 1.0000x reference)
//
#include <hip/hip_runtime.h>

typedef __bf16 bf16_t;
typedef __bf16 bf16x8 __attribute__((ext_vector_type(8)));
typedef __bf16 bf16x4 __attribute__((ext_vector_type(4)));
typedef unsigned short u16x8 __attribute__((ext_vector_type(8)));
typedef unsigned int u32x4 __attribute__((ext_vector_type(4)));
typedef float f32x4 __attribute__((ext_vector_type(4)));
typedef float f32x16 __attribute__((ext_vector_type(16)));
typedef int i32x2 __attribute__((ext_vector_type(2)));

#define NE 8192
#define NN 2048
#define HH 256
#define NSPLIT 4
// 0.125 * log2(e): folded into Q so P = exp2(S)
#define QSCALE 0.18033688011112042f

#if __has_builtin(__builtin_amdgcn_exp2f)
#define EXP2(x) __builtin_amdgcn_exp2f(x)
#else
#define EXP2(x) exp2f(x)
#endif

__device__ inline f32x4 mfma16(bf16x8 a, bf16x8 b, f32x4 c) {
    return __builtin_amdgcn_mfma_f32_16x16x32_bf16(a, b, c, 0, 0, 0);
}
__device__ inline f32x16 mfma32(bf16x8 a, bf16x8 b, f32x16 c) {
    return __builtin_amdgcn_mfma_f32_32x32x16_bf16(a, b, c, 0, 0, 0);
}
__device__ inline unsigned cvtpk(float lo, float hi) {
    unsigned r;
    asm("v_cvt_pk_bf16_f32 %0, %1, %2" : "=v"(r) : "v"(lo), "v"(hi));
    return r;
}
__device__ inline bf16x8 cvt8(float4 a, float4 b) {
    bf16x8 o;
    o[0] = (bf16_t)a.x; o[1] = (bf16_t)a.y; o[2] = (bf16_t)a.z; o[3] = (bf16_t)a.w;
    o[4] = (bf16_t)b.x; o[5] = (bf16_t)b.y; o[6] = (bf16_t)b.z; o[7] = (bf16_t)b.w;
    return o;
}
__device__ inline bf16x4 cvt4(float4 v) {
    bf16x4 o;
    o[0] = (bf16_t)v.x; o[1] = (bf16_t)v.y; o[2] = (bf16_t)v.z; o[3] = (bf16_t)v.w;
    return o;
}

// ---------------------------------------------------------------------------
// convert fp32 -> bf16: edge_features + 5 weight matrices (one pass).
// ---------------------------------------------------------------------------
__global__ __launch_bounds__(256)
void convert_kernel(const float* __restrict__ ef, const float* __restrict__ wq,
                    const float* __restrict__ wo, const float* __restrict__ w1,
                    const float* __restrict__ w2, const float* __restrict__ wn,
                    bf16_t* __restrict__ ebf, bf16_t* __restrict__ bwq,
                    bf16_t* __restrict__ bwo, bf16_t* __restrict__ bw1,
                    bf16_t* __restrict__ bw2, bf16_t* __restrict__ bwn) {
    int i = blockIdx.x * 256 + threadIdx.x;   // 0 .. 524287
    ((bf16x4*)ebf)[i] = cvt4(((const float4*)ef)[i]);
    if (i < 49152) ((bf16x4*)bwq)[i] = cvt4(((const float4*)wq)[i]);
    if (i < 16384) {
        ((bf16x4*)bwo)[i] = cvt4(((const float4*)wo)[i]);
        ((bf16x4*)bw1)[i] = cvt4(((const float4*)w1)[i]);
        ((bf16x4*)bw2)[i] = cvt4(((const float4*)w2)[i]);
        ((bf16x4*)bwn)[i] = cvt4(((const float4*)wn)[i]);
    }
}

// ---------------------------------------------------------------------------
// Generic bf16 GEMM: C = act(A * B^T + bias)  [A: MxK, B: NxK row-major bf16]
// 64x64 tile, BK=64, 256 threads (4 waves, each a 32x32 quadrant)
// QSC: scale cols<256 by QSCALE (folds attention 1/sqrt(d)*log2e into Q)
// ADIV: A is fp32, each row scaled by 1/max(cnt[row],1) during staging
//       (fuses the scatter-mean divide; A read exactly once -> fusion is free).
// ---------------------------------------------------------------------------
template<int ACT, int OUTKIND, int QSC, int ADIV>
__global__ __launch_bounds__(256)
void gemm_kernel(const void* __restrict__ Av, const bf16_t* __restrict__ B,
                 const float* __restrict__ bias, void* __restrict__ out,
                 const float* __restrict__ resid, const float* __restrict__ cntp,
                 int M, int N, int K) {
    __shared__ bf16_t As[64][72];
    __shared__ bf16_t Bs[64][72];
    int tid = threadIdx.x;
    int w = tid >> 6, l = tid & 63, hi = l >> 4, c15 = l & 15;
    int wr = w >> 1, wc = w & 1;
    int brow = blockIdx.x * 64, bcol = blockIdx.y * 64;
    int r = tid >> 2, s = tid & 3;

    f32x4 acc[2][2] = {};

    for (int k0 = 0; k0 < K; k0 += 64) {
        __syncthreads();
        if (ADIV) {
            const float* Af = (const float*)Av;
            const float* p = &Af[(long)(brow + r) * K + k0 + s * 16];
            float4 f0 = *(const float4*)p,       f1 = *(const float4*)(p + 4);
            float4 f2 = *(const float4*)(p + 8), f3 = *(const float4*)(p + 12);
            float rc = 1.0f / fmaxf(cntp[brow + r], 1.0f);
            f0.x *= rc; f0.y *= rc; f0.z *= rc; f0.w *= rc;
            f1.x *= rc; f1.y *= rc; f1.z *= rc; f1.w *= rc;
            f2.x *= rc; f2.y *= rc; f2.z *= rc; f2.w *= rc;
            f3.x *= rc; f3.y *= rc; f3.z *= rc; f3.w *= rc;
            *(bf16x8*)&As[r][s * 16]     = cvt8(f0, f1);
            *(bf16x8*)&As[r][s * 16 + 8] = cvt8(f2, f3);
        } else {
            const bf16_t* Ab = (const bf16_t*)Av;
            *(bf16x8*)&As[r][s * 16]     = *(const bf16x8*)&Ab[(long)(brow + r) * K + k0 + s * 16];
            *(bf16x8*)&As[r][s * 16 + 8] = *(const bf16x8*)&Ab[(long)(brow + r) * K + k0 + s * 16 + 8];
        }
        *(bf16x8*)&Bs[r][s * 16]     = *(const bf16x8*)&B[(long)(bcol + r) * K + k0 + s * 16];
        *(bf16x8*)&Bs[r][s * 16 + 8] = *(const bf16x8*)&B[(long)(bcol + r) * K + k0 + s * 16 + 8];
        __syncthreads();
#pragma unroll
        for (int c = 0; c < 2; ++c) {
            bf16x8 af0 = *(const bf16x8*)&As[wr * 32 + c15][c * 32 + hi * 8];
            bf16x8 af1 = *(const bf16x8*)&As[wr * 32 + 16 + c15][c * 32 + hi * 8];
            bf16x8 bf0 = *(const bf16x8*)&Bs[wc * 32 + c15][c * 32 + hi * 8];
            bf16x8 bf1 = *(const bf16x8*)&Bs[wc * 32 + 16 + c15][c * 32 + hi * 8];
            acc[0][0] = mfma16(af0, bf0, acc[0][0]);
            acc[0][1] = mfma16(af0, bf1, acc[0][1]);
            acc[1][0] = mfma16(af1, bf0, acc[1][0]);
            acc[1][1] = mfma16(af1, bf1, acc[1][1]);
        }
    }

    float sc = (QSC && bcol < 256) ? QSCALE : 1.0f;
#pragma unroll
    for (int i = 0; i < 2; ++i)
#pragma unroll
        for (int j = 0; j < 2; ++j)
#pragma unroll
            for (int rg = 0; rg < 4; ++rg) {
                int row = brow + wr * 32 + i * 16 + hi * 4 + rg;
                int col = bcol + wc * 32 + j * 16 + c15;
                float v = (acc[i][j][rg] + bias[col]) * sc;
                if (ACT) v = fmaxf(v, 0.0f);
                if (OUTKIND == 0) {
                    ((float*)out)[(long)row * N + col] = v;
                } else if (OUTKIND == 1) {
                    ((bf16_t*)out)[(long)row * N + col] = (bf16_t)v;
                } else {
                    ((float*)out)[(long)row * N + col] =
                        resid[(long)row * N + col] + fmaxf(v, 0.0f);
                }
            }
}

// ---------------------------------------------------------------------------
// Flash attention, 32x32x16 MFMA, swapped QK^T (S^T = K Q^T): softmax is
// lane-local, P feeds PV's B-operand via cvt_pk + permlane32_swap (no LDS).
// Q pre-scaled by 0.125*log2e so P = exp2(S).
// Block: 256 thr = 4 waves, each wave 64 q-rows (2 qt sub-tiles) -> q-block 256.
// grid = dim3(128, NSPLIT=4) = 512 blocks = exactly 2 blocks/CU — matches the
// register-file residency cap (~192 unified VGPR/wave -> 2 waves/SIMD), so
// NSPLIT>4 adds no occupancy, only Opart traffic (R5 vs R2 post-mortems).
// NO s_setprio (R6: fences the scheduler here, -9 us). ~880 TF effective ==
// the 2-barrier-structure ceiling.
// ---------------------------------------------------------------------------
__global__ __launch_bounds__(256, 2)
void attn_kernel(const bf16_t* __restrict__ qkv, bf16_t* __restrict__ Opart,
                 float* __restrict__ lpart) {
    __shared__ char smem[36864];
    bf16_t (*Ks)[64][72] = (bf16_t (*)[64][72])smem;             // [buf][kv][d]
    bf16_t (*Vt)[64][72] = (bf16_t (*)[64][72])(smem + 18432);   // [buf][d][kv]

    int h = blockIdx.x & 3, qb = blockIdx.x >> 2, sp = blockIdx.y;
    int q0 = qb * 256;
    int tid = threadIdx.x;
    int wv = tid >> 6, l = tid & 63, l31 = l & 31, h8 = l >> 5;

    bf16x8 qf[2][4];
#pragma unroll
    for (int qt = 0; qt < 2; ++qt)
#pragma unroll
        for (int dc = 0; dc < 4; ++dc)
            qf[qt][dc] = *(const bf16x8*)&qkv[
                (size_t)(q0 + wv * 64 + qt * 32 + l31) * 768 + h * 64 + dc * 16 + h8 * 8];

    f32x16 o[2][2];
#pragma unroll
    for (int a = 0; a < 2; ++a)
#pragma unroll
        for (int b = 0; b < 2; ++b)
#pragma unroll
            for (int r = 0; r < 16; ++r) o[a][b][r] = 0.f;
    float ls[2] = {0.f, 0.f};

    int kr = tid >> 2, ksc = tid & 3;
    int vp = tid & 31, vc = tid >> 5;
    int kv0 = sp * (NE / NSPLIT);
    const int NT = (NE / NSPLIT) / 64;

    bf16x8 kst0, kst1, vst0, vst1;
    {
        const bf16_t* ksrc = &qkv[(size_t)(kv0 + kr) * 768 + 256 + h * 64 + ksc * 16];
        kst0 = *(const bf16x8*)ksrc; kst1 = *(const bf16x8*)(ksrc + 8);
        const bf16_t* vsrc = &qkv[(size_t)(kv0 + 2 * vp) * 768 + 512 + h * 64 + vc * 8];
        vst0 = *(const bf16x8*)vsrc; vst1 = *(const bf16x8*)(vsrc + 768);
    }
    {
        *(bf16x8*)&Ks[0][kr][ksc * 16]     = kst0;
        *(bf16x8*)&Ks[0][kr][ksc * 16 + 8] = kst1;
        u16x8 ua = __builtin_bit_cast(u16x8, vst0), ub = __builtin_bit_cast(u16x8, vst1);
#pragma unroll
        for (int j = 0; j < 8; ++j) {
            unsigned wd = (unsigned)ua[j] | ((unsigned)ub[j] << 16);
            *(unsigned*)&Vt[0][vc * 8 + j][2 * vp] = wd;
        }
    }

    for (int t = 0; t < NT; ++t) {
        int cur = t & 1;
        __syncthreads();
        if (t + 1 < NT) {
            int kt = kv0 + (t + 1) * 64;
            const bf16_t* ksrc = &qkv[(size_t)(kt + kr) * 768 + 256 + h * 64 + ksc * 16];
            kst0 = *(const bf16x8*)ksrc; kst1 = *(const bf16x8*)(ksrc + 8);
            const bf16_t* vsrc = &qkv[(size_t)(kt + 2 * vp) * 768 + 512 + h * 64 + vc * 8];
            vst0 = *(const bf16x8*)vsrc; vst1 = *(const bf16x8*)(vsrc + 768);
        }

#pragma unroll
        for (int kvt = 0; kvt < 2; ++kvt) {
            bf16x8 kf[4];
#pragma unroll
            for (int dc = 0; dc < 4; ++dc)
                kf[dc] = *(const bf16x8*)&Ks[cur][kvt * 32 + l31][dc * 16 + h8 * 8];
            f32x16 s[2];
#pragma unroll
            for (int qt = 0; qt < 2; ++qt) {
#pragma unroll
                for (int r = 0; r < 16; ++r) s[qt][r] = 0.f;
#pragma unroll
                for (int dc = 0; dc < 4; ++dc)
                    s[qt] = mfma32(kf[dc], qf[qt][dc], s[qt]);
            }
            bf16x8 bfr[2][2];
#pragma unroll
            for (int qt = 0; qt < 2; ++qt) {
                float p[16];
#pragma unroll
                for (int r = 0; r < 16; ++r) { p[r] = EXP2(s[qt][r]); ls[qt] += p[r]; }
#pragma unroll
                for (int half = 0; half < 2; ++half) {
                    i32x2 r0 = __builtin_amdgcn_permlane32_swap(
                        (int)cvtpk(p[8 * half + 0], p[8 * half + 1]),
                        (int)cvtpk(p[8 * half + 4], p[8 * half + 5]), false, false);
                    i32x2 r1 = __builtin_amdgcn_permlane32_swap(
                        (int)cvtpk(p[8 * half + 2], p[8 * half + 3]),
                        (int)cvtpk(p[8 * half + 6], p[8 * half + 7]), false, false);
                    u32x4 wds;
                    wds[0] = (unsigned)r0[0]; wds[1] = (unsigned)r1[0];
                    wds[2] = (unsigned)r0[1]; wds[3] = (unsigned)r1[1];
                    bfr[qt][half] = __builtin_bit_cast(bf16x8, wds);
                }
            }
#pragma unroll
            for (int dt = 0; dt < 2; ++dt) {
                bf16x8 vf[2];
#pragma unroll
                for (int half = 0; half < 2; ++half)
                    vf[half] = *(const bf16x8*)&Vt[cur][dt * 32 + l31][(kvt * 2 + half) * 16 + h8 * 8];
#pragma unroll
                for (int qt = 0; qt < 2; ++qt)
#pragma unroll
                    for (int half = 0; half < 2; ++half)
                        o[dt][qt] = mfma32(vf[half], bfr[qt][half], o[dt][qt]);
            }
        }

        if (t + 1 < NT) {
            int nb = (t + 1) & 1;
            *(bf16x8*)&Ks[nb][kr][ksc * 16]     = kst0;
            *(bf16x8*)&Ks[nb][kr][ksc * 16 + 8] = kst1;
            u16x8 ua = __builtin_bit_cast(u16x8, vst0), ub = __builtin_bit_cast(u16x8, vst1);
#pragma unroll
            for (int j = 0; j < 8; ++j) {
                unsigned wd = (unsigned)ua[j] | ((unsigned)ub[j] << 16);
                *(unsigned*)&Vt[nb][vc * 8 + j][2 * vp] = wd;
            }
        }
    }

#pragma unroll
    for (int qt = 0; qt < 2; ++qt) {
        float lt = ls[qt] + __shfl_xor(ls[qt], 32);
        if (l < 32)
            lpart[((size_t)sp * 4 + h) * NE + q0 + wv * 64 + qt * 32 + l31] = lt;
    }

    float* Of = (float*)smem;
#pragma unroll
    for (int pass = 0; pass < 2; ++pass) {
        __syncthreads();
        if ((wv >> 1) == pass) {
#pragma unroll
            for (int dt = 0; dt < 2; ++dt)
#pragma unroll
                for (int qt = 0; qt < 2; ++qt)
#pragma unroll
                    for (int r = 0; r < 16; ++r) {
                        int qrel = (wv & 1) * 64 + qt * 32 + l31;
                        int d = dt * 32 + (r & 3) + 8 * (r >> 2) + 4 * h8;
                        Of[qrel * 68 + d] = o[dt][qt][r];
                    }
        }
        __syncthreads();
        {
            int rr = tid >> 1, hf = tid & 1;
            bf16_t* dst = &Opart[(size_t)sp * NE * 256 +
                                 (size_t)(q0 + pass * 128 + rr) * 256 + h * 64 + hf * 32];
#pragma unroll
            for (int i = 0; i < 4; ++i) {
                float4 va = *(float4*)&Of[rr * 68 + hf * 32 + i * 8];
                float4 vb = *(float4*)&Of[rr * 68 + hf * 32 + i * 8 + 4];
                bf16x8 ob;
                ob[0] = (bf16_t)va.x; ob[1] = (bf16_t)va.y;
                ob[2] = (bf16_t)va.z; ob[3] = (bf16_t)va.w;
                ob[4] = (bf16_t)vb.x; ob[5] = (bf16_t)vb.y;
                ob[6] = (bf16_t)vb.z; ob[7] = (bf16_t)vb.w;
                *(bf16x8*)&dst[i * 8] = ob;
            }
        }
    }
}

// ctx = bf16( sum_sp Opart / sum_sp lpart ); one bf16x8 slot per thread
__global__ __launch_bounds__(256)
void attn_merge_kernel(const bf16_t* __restrict__ Opart, const float* __restrict__ lpart,
                       bf16_t* __restrict__ ctx) {
    int i = blockIdx.x * 256 + threadIdx.x;
    int q = i >> 5;
    int h = (i & 31) >> 3;
    float sum[8] = {};
    float lsum = 0.f;
#pragma unroll
    for (int sp = 0; sp < NSPLIT; ++sp) {
        bf16x8 v = ((const bf16x8*)Opart)[(size_t)sp * (NE * 32) + i];
#pragma unroll
        for (int j = 0; j < 8; ++j) sum[j] += (float)v[j];
        lsum += lpart[((size_t)sp * 4 + h) * NE + q];
    }
    float rl = 1.0f / lsum;
    bf16x8 c;
#pragma unroll
    for (int j = 0; j < 8; ++j) c[j] = (bf16_t)(sum[j] * rl);
    ((bf16x8*)ctx)[i] = c;
}

// ---------------------------------------------------------------------------
// LayerNorm over rows of 256: out = LN(x + y) * g + b
// XBF16/YBF16: inputs bf16. WRITE_F32/WRITE_BF16 select outputs.
// SCATTER: fused scatter-add of the fp32 LN output into per-node accumulators
// (kills the standalone scatter dispatch + its 8 MB re-read).
// ---------------------------------------------------------------------------
template<int XBF16, int YBF16, int WRITE_F32, int WRITE_BF16, int SCATTER>
__global__ __launch_bounds__(256)
void ln_kernel(const void* __restrict__ xv, const void* __restrict__ yv,
               const float* __restrict__ g, const float* __restrict__ b,
               float* __restrict__ outf, bf16_t* __restrict__ outb,
               const int* __restrict__ ei, float* __restrict__ acc,
               float* __restrict__ cnt) {
    int row = blockIdx.x * 4 + (threadIdx.x >> 6);
    int l = threadIdx.x & 63;
    float x0, x1, x2, x3, y0, y1, y2, y3;
    if (XBF16) {
        bf16x4 t = ((const bf16x4*)xv)[(long)row * 64 + l];
        x0 = (float)t[0]; x1 = (float)t[1]; x2 = (float)t[2]; x3 = (float)t[3];
    } else {
        float4 t = ((const float4*)xv)[(long)row * 64 + l];
        x0 = t.x; x1 = t.y; x2 = t.z; x3 = t.w;
    }
    if (YBF16) {
        bf16x4 t = ((const bf16x4*)yv)[(long)row * 64 + l];
        y0 = (float)t[0]; y1 = (float)t[1]; y2 = (float)t[2]; y3 = (float)t[3];
    } else {
        float4 t = ((const float4*)yv)[(long)row * 64 + l];
        y0 = t.x; y1 = t.y; y2 = t.z; y3 = t.w;
    }
    float a0 = x0 + y0, a1 = x1 + y1, a2 = x2 + y2, a3 = x3 + y3;

    float s = a0 + a1 + a2 + a3;
#pragma unroll
    for (int off = 1; off < 64; off <<= 1) s += __shfl_xor(s, off);
    float mu = s * (1.0f / 256.0f);

    float d0 = a0 - mu, d1 = a1 - mu, d2 = a2 - mu, d3 = a3 - mu;
    float q = d0 * d0 + d1 * d1 + d2 * d2 + d3 * d3;
#pragma unroll
    for (int off = 1; off < 64; off <<= 1) q += __shfl_xor(q, off);
    float rs = rsqrtf(q * (1.0f / 256.0f) + 1e-5f);

    float4 gg = ((const float4*)g)[l];
    float4 bb = ((const float4*)b)[l];
    float o0 = d0 * rs * gg.x + bb.x;
    float o1 = d1 * rs * gg.y + bb.y;
    float o2 = d2 * rs * gg.z + bb.z;
    float o3 = d3 * rs * gg.w + bb.w;
    if (WRITE_F32) {
        float4 ov; ov.x = o0; ov.y = o1; ov.z = o2; ov.w = o3;
        ((float4*)&outf[(long)row * 256])[l] = ov;
    }
    if (WRITE_BF16) {
        bf16x4 ob;
        ob[0] = (bf16_t)o0; ob[1] = (bf16_t)o1; ob[2] = (bf16_t)o2; ob[3] = (bf16_t)o3;
        ((bf16x4*)&outb[(long)row * 256])[l] = ob;
    }
    if (SCATTER) {
        int dst = ei[NE + row];
        float* ap = &acc[(long)dst * 256 + l * 4];
        atomicAdd(ap + 0, o0);
        atomicAdd(ap + 1, o1);
        atomicAdd(ap + 2, o2);
        atomicAdd(ap + 3, o3);
        if (l == 0) atomicAdd(&cnt[dst], 1.0f);
    }
}

// ---------------------------------------------------------------------------
extern "C" void kernel_launch(void* const* d_in, const int* in_sizes, int n_in,
                              void* d_out, int out_size, void* d_ws, size_t ws_size,
                              hipStream_t stream) {
    const float* node_features = (const float*)d_in[0];
    const float* edge_features = (const float*)d_in[1];
    const float* in_proj_w  = (const float*)d_in[2];
    const float* in_proj_b  = (const float*)d_in[3];
    const float* out_proj_w = (const float*)d_in[4];
    const float* out_proj_b = (const float*)d_in[5];
    const float* mlp_w1 = (const float*)d_in[6];
    const float* mlp_b1 = (const float*)d_in[7];
    const float* mlp_w2 = (const float*)d_in[8];
    const float* mlp_b2 = (const float*)d_in[9];
    const float* nu_w   = (const float*)d_in[10];
    const float* nu_b   = (const float*)d_in[11];
    const float* ln1_g  = (const float*)d_in[12];
    const float* ln1_b  = (const float*)d_in[13];
    const float* ln2_g  = (const float*)d_in[14];
    const float* ln2_b  = (const float*)d_in[15];
    const int*   edge_index = (const int*)d_in[16];

    char* ws = (char*)d_ws;
    size_t off = 0;
    auto alloc = [&](size_t bytes) {
        char* p = ws + off;
        off = (off + bytes + 255) & ~(size_t)255;
        return p;
    };
    // region A: persistent across the whole launch
    bf16_t* ebf   = (bf16_t*)alloc(NE * HH * 2);
    bf16_t* bwq   = (bf16_t*)alloc(768 * 256 * 2);
    bf16_t* bwo   = (bf16_t*)alloc(256 * 256 * 2);
    bf16_t* bw1   = (bf16_t*)alloc(256 * 256 * 2);
    bf16_t* bw2   = (bf16_t*)alloc(256 * 256 * 2);
    bf16_t* bwn   = (bf16_t*)alloc(256 * 256 * 2);
    bf16_t* qkv   = (bf16_t*)alloc((size_t)NE * 768 * 2);
    bf16_t* ctx   = (bf16_t*)alloc((size_t)NE * HH * 2);
    float*  lpart = (float*)alloc((size_t)NSPLIT * 4 * NE * 4);
    float*  acc   = (float*)alloc((size_t)(NN * HH + NN) * 4);
    float*  cnt   = acc + (size_t)NN * HH;
    // region B: Opart dies at merge; post-attention activations born after
    size_t offB = off;
    bf16_t* Opart = (bf16_t*)alloc((size_t)NSPLIT * NE * HH * 2);   // 16.8 MB bf16
    off = offB;
    bf16_t* attended = (bf16_t*)alloc((size_t)NE * HH * 2);
    bf16_t* e1b   = (bf16_t*)alloc((size_t)NE * HH * 2);
    bf16_t* hbuf  = (bf16_t*)alloc((size_t)NE * HH * 2);
    bf16_t* mlpout = (bf16_t*)alloc((size_t)NE * HH * 2);

    float* nout = (float*)d_out;
    float* eout = (float*)d_out + (size_t)NN * HH;

    convert_kernel<<<2048, 256, 0, stream>>>(edge_features, in_proj_w, out_proj_w,
                                             mlp_w1, mlp_w2, nu_w,
                                             ebf, bwq, bwo, bw1, bw2, bwn);

    // zero node accumulators early (needed by the fused LN2 scatter)
    hipMemsetAsync(acc, 0, (size_t)(NN * HH + NN) * 4, stream);

    // qkv = ebf @ in_proj_w^T + b -> bf16 [NE,768]; Q cols pre-scaled
    gemm_kernel<0, 1, 1, 0><<<dim3(NE / 64, 768 / 64), 256, 0, stream>>>(
        ebf, bwq, in_proj_b, qkv, nullptr, nullptr, NE, 768, 256);

    attn_kernel<<<dim3(128, NSPLIT), 256, 0, stream>>>(qkv, Opart, lpart);
    attn_merge_kernel<<<1024, 256, 0, stream>>>(Opart, lpart, ctx);

    // attended = ctx @ out_proj_w^T + b -> bf16 (read once by LN1)
    gemm_kernel<0, 1, 0, 0><<<dim3(NE / 64, 256 / 64), 256, 0, stream>>>(
        ctx, bwo, out_proj_b, attended, nullptr, nullptr, NE, 256, 256);

    // e1 = LN(edge_features + attended) -> e1b bf16 only
    ln_kernel<0, 1, 0, 1, 0><<<NE / 4, 256, 0, stream>>>(
        edge_features, attended, ln1_g, ln1_b, nullptr, e1b,
        nullptr, nullptr, nullptr);

    // h = relu(e1 @ w1^T + b1) -> bf16
    gemm_kernel<1, 1, 0, 0><<<dim3(NE / 64, 256 / 64), 256, 0, stream>>>(
        e1b, bw1, mlp_b1, hbuf, nullptr, nullptr, NE, 256, 256);

    // mlpout = h @ w2^T + b2 -> bf16 (read once by LN2)
    gemm_kernel<0, 1, 0, 0><<<dim3(NE / 64, 256 / 64), 256, 0, stream>>>(
        hbuf, bw2, mlp_b2, mlpout, nullptr, nullptr, NE, 256, 256);

    // e = LN(e1 + mlpout) -> d_out (second output) + fused scatter-add
    ln_kernel<1, 1, 1, 0, 1><<<NE / 4, 256, 0, stream>>>(
        e1b, mlpout, ln2_g, ln2_b, eout, nullptr,
        edge_index, acc, cnt);

    // n = node_features + relu((acc/cnt) @ nu_w^T + nu_b) -> d_out (first output)
    gemm_kernel<0, 2, 0, 1><<<dim3(NN / 64, 256 / 64), 256, 0, stream>>>(
        acc, bwn, nu_b, nout, node_features, cnt, NN, 256, 256);
}

// Round 11
// 143.569 us; speedup vs baseline: 1.1299x; 1.1299x over previous
//
#include <hip/hip_runtime.h>

typedef __bf16 bf16_t;
typedef __bf16 bf16x8 __attribute__((ext_vector_type(8)));
typedef __bf16 bf16x4 __attribute__((ext_vector_type(4)));
typedef unsigned short u16x8 __attribute__((ext_vector_type(8)));
typedef unsigned int u32x4 __attribute__((ext_vector_type(4)));
typedef float f32x4 __attribute__((ext_vector_type(4)));
typedef float f32x16 __attribute__((ext_vector_type(16)));
typedef int i32x2 __attribute__((ext_vector_type(2)));

#define NE 8192
#define NN 2048
#define HH 256
#define NSPLIT 4
// 0.125 * log2(e): folded into Q so P = exp2(S)
#define QSCALE 0.18033688011112042f

#if __has_builtin(__builtin_amdgcn_exp2f)
#define EXP2(x) __builtin_amdgcn_exp2f(x)
#else
#define EXP2(x) exp2f(x)
#endif

__device__ inline f32x4 mfma16(bf16x8 a, bf16x8 b, f32x4 c) {
    return __builtin_amdgcn_mfma_f32_16x16x32_bf16(a, b, c, 0, 0, 0);
}
__device__ inline f32x16 mfma32(bf16x8 a, bf16x8 b, f32x16 c) {
    return __builtin_amdgcn_mfma_f32_32x32x16_bf16(a, b, c, 0, 0, 0);
}
__device__ inline unsigned cvtpk(float lo, float hi) {
    unsigned r;
    asm("v_cvt_pk_bf16_f32 %0, %1, %2" : "=v"(r) : "v"(lo), "v"(hi));
    return r;
}
__device__ inline bf16x8 cvt8(float4 a, float4 b) {
    bf16x8 o;
    o[0] = (bf16_t)a.x; o[1] = (bf16_t)a.y; o[2] = (bf16_t)a.z; o[3] = (bf16_t)a.w;
    o[4] = (bf16_t)b.x; o[5] = (bf16_t)b.y; o[6] = (bf16_t)b.z; o[7] = (bf16_t)b.w;
    return o;
}
__device__ inline bf16x4 cvt4(float4 v) {
    bf16x4 o;
    o[0] = (bf16_t)v.x; o[1] = (bf16_t)v.y; o[2] = (bf16_t)v.z; o[3] = (bf16_t)v.w;
    return o;
}

// ---------------------------------------------------------------------------
// convert fp32 -> bf16: edge_features + 5 weight matrices (one pass).
// ---------------------------------------------------------------------------
__global__ __launch_bounds__(256)
void convert_kernel(const float* __restrict__ ef, const float* __restrict__ wq,
                    const float* __restrict__ wo, const float* __restrict__ w1,
                    const float* __restrict__ w2, const float* __restrict__ wn,
                    bf16_t* __restrict__ ebf, bf16_t* __restrict__ bwq,
                    bf16_t* __restrict__ bwo, bf16_t* __restrict__ bw1,
                    bf16_t* __restrict__ bw2, bf16_t* __restrict__ bwn) {
    int i = blockIdx.x * 256 + threadIdx.x;   // 0 .. 524287
    ((bf16x4*)ebf)[i] = cvt4(((const float4*)ef)[i]);
    if (i < 49152) ((bf16x4*)bwq)[i] = cvt4(((const float4*)wq)[i]);
    if (i < 16384) {
        ((bf16x4*)bwo)[i] = cvt4(((const float4*)wo)[i]);
        ((bf16x4*)bw1)[i] = cvt4(((const float4*)w1)[i]);
        ((bf16x4*)bw2)[i] = cvt4(((const float4*)w2)[i]);
        ((bf16x4*)bwn)[i] = cvt4(((const float4*)wn)[i]);
    }
}

// ---------------------------------------------------------------------------
// Generic bf16 GEMM: C = act(A * B^T + bias)  [A: MxK, B: NxK row-major bf16]
// 64x64 tile, BK=64, 256 threads (4 waves, each a 32x32 quadrant)
// QSC: scale cols<256 by QSCALE (folds attention 1/sqrt(d)*log2e into Q)
// ADIV: A is fp32, each row scaled by 1/max(cnt[row],1) during staging
//       (fuses the scatter-mean divide; A read exactly once -> fusion is free).
// ---------------------------------------------------------------------------
template<int ACT, int OUTKIND, int QSC, int ADIV>
__global__ __launch_bounds__(256)
void gemm_kernel(const void* __restrict__ Av, const bf16_t* __restrict__ B,
                 const float* __restrict__ bias, void* __restrict__ out,
                 const float* __restrict__ resid, const float* __restrict__ cntp,
                 int M, int N, int K) {
    __shared__ bf16_t As[64][72];
    __shared__ bf16_t Bs[64][72];
    int tid = threadIdx.x;
    int w = tid >> 6, l = tid & 63, hi = l >> 4, c15 = l & 15;
    int wr = w >> 1, wc = w & 1;
    int brow = blockIdx.x * 64, bcol = blockIdx.y * 64;
    int r = tid >> 2, s = tid & 3;

    f32x4 acc[2][2] = {};

    for (int k0 = 0; k0 < K; k0 += 64) {
        __syncthreads();
        if (ADIV) {
            const float* Af = (const float*)Av;
            const float* p = &Af[(long)(brow + r) * K + k0 + s * 16];
            float4 f0 = *(const float4*)p,       f1 = *(const float4*)(p + 4);
            float4 f2 = *(const float4*)(p + 8), f3 = *(const float4*)(p + 12);
            float rc = 1.0f / fmaxf(cntp[brow + r], 1.0f);
            f0.x *= rc; f0.y *= rc; f0.z *= rc; f0.w *= rc;
            f1.x *= rc; f1.y *= rc; f1.z *= rc; f1.w *= rc;
            f2.x *= rc; f2.y *= rc; f2.z *= rc; f2.w *= rc;
            f3.x *= rc; f3.y *= rc; f3.z *= rc; f3.w *= rc;
            *(bf16x8*)&As[r][s * 16]     = cvt8(f0, f1);
            *(bf16x8*)&As[r][s * 16 + 8] = cvt8(f2, f3);
        } else {
            const bf16_t* Ab = (const bf16_t*)Av;
            *(bf16x8*)&As[r][s * 16]     = *(const bf16x8*)&Ab[(long)(brow + r) * K + k0 + s * 16];
            *(bf16x8*)&As[r][s * 16 + 8] = *(const bf16x8*)&Ab[(long)(brow + r) * K + k0 + s * 16 + 8];
        }
        *(bf16x8*)&Bs[r][s * 16]     = *(const bf16x8*)&B[(long)(bcol + r) * K + k0 + s * 16];
        *(bf16x8*)&Bs[r][s * 16 + 8] = *(const bf16x8*)&B[(long)(bcol + r) * K + k0 + s * 16 + 8];
        __syncthreads();
#pragma unroll
        for (int c = 0; c < 2; ++c) {
            bf16x8 af0 = *(const bf16x8*)&As[wr * 32 + c15][c * 32 + hi * 8];
            bf16x8 af1 = *(const bf16x8*)&As[wr * 32 + 16 + c15][c * 32 + hi * 8];
            bf16x8 bf0 = *(const bf16x8*)&Bs[wc * 32 + c15][c * 32 + hi * 8];
            bf16x8 bf1 = *(const bf16x8*)&Bs[wc * 32 + 16 + c15][c * 32 + hi * 8];
            acc[0][0] = mfma16(af0, bf0, acc[0][0]);
            acc[0][1] = mfma16(af0, bf1, acc[0][1]);
            acc[1][0] = mfma16(af1, bf0, acc[1][0]);
            acc[1][1] = mfma16(af1, bf1, acc[1][1]);
        }
    }

    float sc = (QSC && bcol < 256) ? QSCALE : 1.0f;
#pragma unroll
    for (int i = 0; i < 2; ++i)
#pragma unroll
        for (int j = 0; j < 2; ++j)
#pragma unroll
            for (int rg = 0; rg < 4; ++rg) {
                int row = brow + wr * 32 + i * 16 + hi * 4 + rg;
                int col = bcol + wc * 32 + j * 16 + c15;
                float v = (acc[i][j][rg] + bias[col]) * sc;
                if (ACT) v = fmaxf(v, 0.0f);
                if (OUTKIND == 0) {
                    ((float*)out)[(long)row * N + col] = v;
                } else if (OUTKIND == 1) {
                    ((bf16_t*)out)[(long)row * N + col] = (bf16_t)v;
                } else {
                    ((float*)out)[(long)row * N + col] =
                        resid[(long)row * N + col] + fmaxf(v, 0.0f);
                }
            }
}

// ---------------------------------------------------------------------------
// Flash attention, 32x32x16 MFMA, swapped QK^T (S^T = K Q^T): softmax is
// lane-local, P feeds PV's B-operand via cvt_pk + permlane32_swap (no LDS).
// Q pre-scaled by 0.125*log2e so P = exp2(S).
// Block: 256 thr = 4 waves, each wave 64 q-rows (2 qt sub-tiles) -> q-block 256.
// grid = dim3(128, NSPLIT=4) = 512 blocks = exactly 2 blocks/CU — matches the
// register-file residency cap (~192 unified VGPR/wave -> 2 waves/SIMD).
// NO s_setprio (R6: fences the scheduler here, -9 us). ~880 TF effective ==
// the 2-barrier-structure ceiling.
// ---------------------------------------------------------------------------
__global__ __launch_bounds__(256, 2)
void attn_kernel(const bf16_t* __restrict__ qkv, bf16_t* __restrict__ Opart,
                 float* __restrict__ lpart) {
    __shared__ char smem[36864];
    bf16_t (*Ks)[64][72] = (bf16_t (*)[64][72])smem;             // [buf][kv][d]
    bf16_t (*Vt)[64][72] = (bf16_t (*)[64][72])(smem + 18432);   // [buf][d][kv]

    int h = blockIdx.x & 3, qb = blockIdx.x >> 2, sp = blockIdx.y;
    int q0 = qb * 256;
    int tid = threadIdx.x;
    int wv = tid >> 6, l = tid & 63, l31 = l & 31, h8 = l >> 5;

    bf16x8 qf[2][4];
#pragma unroll
    for (int qt = 0; qt < 2; ++qt)
#pragma unroll
        for (int dc = 0; dc < 4; ++dc)
            qf[qt][dc] = *(const bf16x8*)&qkv[
                (size_t)(q0 + wv * 64 + qt * 32 + l31) * 768 + h * 64 + dc * 16 + h8 * 8];

    f32x16 o[2][2];
#pragma unroll
    for (int a = 0; a < 2; ++a)
#pragma unroll
        for (int b = 0; b < 2; ++b)
#pragma unroll
            for (int r = 0; r < 16; ++r) o[a][b][r] = 0.f;
    float ls[2] = {0.f, 0.f};

    int kr = tid >> 2, ksc = tid & 3;
    int vp = tid & 31, vc = tid >> 5;
    int kv0 = sp * (NE / NSPLIT);
    const int NT = (NE / NSPLIT) / 64;

    bf16x8 kst0, kst1, vst0, vst1;
    {
        const bf16_t* ksrc = &qkv[(size_t)(kv0 + kr) * 768 + 256 + h * 64 + ksc * 16];
        kst0 = *(const bf16x8*)ksrc; kst1 = *(const bf16x8*)(ksrc + 8);
        const bf16_t* vsrc = &qkv[(size_t)(kv0 + 2 * vp) * 768 + 512 + h * 64 + vc * 8];
        vst0 = *(const bf16x8*)vsrc; vst1 = *(const bf16x8*)(vsrc + 768);
    }
    {
        *(bf16x8*)&Ks[0][kr][ksc * 16]     = kst0;
        *(bf16x8*)&Ks[0][kr][ksc * 16 + 8] = kst1;
        u16x8 ua = __builtin_bit_cast(u16x8, vst0), ub = __builtin_bit_cast(u16x8, vst1);
#pragma unroll
        for (int j = 0; j < 8; ++j) {
            unsigned wd = (unsigned)ua[j] | ((unsigned)ub[j] << 16);
            *(unsigned*)&Vt[0][vc * 8 + j][2 * vp] = wd;
        }
    }

    for (int t = 0; t < NT; ++t) {
        int cur = t & 1;
        __syncthreads();
        if (t + 1 < NT) {
            int kt = kv0 + (t + 1) * 64;
            const bf16_t* ksrc = &qkv[(size_t)(kt + kr) * 768 + 256 + h * 64 + ksc * 16];
            kst0 = *(const bf16x8*)ksrc; kst1 = *(const bf16x8*)(ksrc + 8);
            const bf16_t* vsrc = &qkv[(size_t)(kt + 2 * vp) * 768 + 512 + h * 64 + vc * 8];
            vst0 = *(const bf16x8*)vsrc; vst1 = *(const bf16x8*)(vsrc + 768);
        }

#pragma unroll
        for (int kvt = 0; kvt < 2; ++kvt) {
            bf16x8 kf[4];
#pragma unroll
            for (int dc = 0; dc < 4; ++dc)
                kf[dc] = *(const bf16x8*)&Ks[cur][kvt * 32 + l31][dc * 16 + h8 * 8];
            f32x16 s[2];
#pragma unroll
            for (int qt = 0; qt < 2; ++qt) {
#pragma unroll
                for (int r = 0; r < 16; ++r) s[qt][r] = 0.f;
#pragma unroll
                for (int dc = 0; dc < 4; ++dc)
                    s[qt] = mfma32(kf[dc], qf[qt][dc], s[qt]);
            }
            bf16x8 bfr[2][2];
#pragma unroll
            for (int qt = 0; qt < 2; ++qt) {
                float p[16];
#pragma unroll
                for (int r = 0; r < 16; ++r) { p[r] = EXP2(s[qt][r]); ls[qt] += p[r]; }
#pragma unroll
                for (int half = 0; half < 2; ++half) {
                    i32x2 r0 = __builtin_amdgcn_permlane32_swap(
                        (int)cvtpk(p[8 * half + 0], p[8 * half + 1]),
                        (int)cvtpk(p[8 * half + 4], p[8 * half + 5]), false, false);
                    i32x2 r1 = __builtin_amdgcn_permlane32_swap(
                        (int)cvtpk(p[8 * half + 2], p[8 * half + 3]),
                        (int)cvtpk(p[8 * half + 6], p[8 * half + 7]), false, false);
                    u32x4 wds;
                    wds[0] = (unsigned)r0[0]; wds[1] = (unsigned)r1[0];
                    wds[2] = (unsigned)r0[1]; wds[3] = (unsigned)r1[1];
                    bfr[qt][half] = __builtin_bit_cast(bf16x8, wds);
                }
            }
#pragma unroll
            for (int dt = 0; dt < 2; ++dt) {
                bf16x8 vf[2];
#pragma unroll
                for (int half = 0; half < 2; ++half)
                    vf[half] = *(const bf16x8*)&Vt[cur][dt * 32 + l31][(kvt * 2 + half) * 16 + h8 * 8];
#pragma unroll
                for (int qt = 0; qt < 2; ++qt)
#pragma unroll
                    for (int half = 0; half < 2; ++half)
                        o[dt][qt] = mfma32(vf[half], bfr[qt][half], o[dt][qt]);
            }
        }

        if (t + 1 < NT) {
            int nb = (t + 1) & 1;
            *(bf16x8*)&Ks[nb][kr][ksc * 16]     = kst0;
            *(bf16x8*)&Ks[nb][kr][ksc * 16 + 8] = kst1;
            u16x8 ua = __builtin_bit_cast(u16x8, vst0), ub = __builtin_bit_cast(u16x8, vst1);
#pragma unroll
            for (int j = 0; j < 8; ++j) {
                unsigned wd = (unsigned)ua[j] | ((unsigned)ub[j] << 16);
                *(unsigned*)&Vt[nb][vc * 8 + j][2 * vp] = wd;
            }
        }
    }

#pragma unroll
    for (int qt = 0; qt < 2; ++qt) {
        float lt = ls[qt] + __shfl_xor(ls[qt], 32);
        if (l < 32)
            lpart[((size_t)sp * 4 + h) * NE + q0 + wv * 64 + qt * 32 + l31] = lt;
    }

    float* Of = (float*)smem;
#pragma unroll
    for (int pass = 0; pass < 2; ++pass) {
        __syncthreads();
        if ((wv >> 1) == pass) {
#pragma unroll
            for (int dt = 0; dt < 2; ++dt)
#pragma unroll
                for (int qt = 0; qt < 2; ++qt)
#pragma unroll
                    for (int r = 0; r < 16; ++r) {
                        int qrel = (wv & 1) * 64 + qt * 32 + l31;
                        int d = dt * 32 + (r & 3) + 8 * (r >> 2) + 4 * h8;
                        Of[qrel * 68 + d] = o[dt][qt][r];
                    }
        }
        __syncthreads();
        {
            int rr = tid >> 1, hf = tid & 1;
            bf16_t* dst = &Opart[(size_t)sp * NE * 256 +
                                 (size_t)(q0 + pass * 128 + rr) * 256 + h * 64 + hf * 32];
#pragma unroll
            for (int i = 0; i < 4; ++i) {
                float4 va = *(float4*)&Of[rr * 68 + hf * 32 + i * 8];
                float4 vb = *(float4*)&Of[rr * 68 + hf * 32 + i * 8 + 4];
                bf16x8 ob;
                ob[0] = (bf16_t)va.x; ob[1] = (bf16_t)va.y;
                ob[2] = (bf16_t)va.z; ob[3] = (bf16_t)va.w;
                ob[4] = (bf16_t)vb.x; ob[5] = (bf16_t)vb.y;
                ob[6] = (bf16_t)vb.z; ob[7] = (bf16_t)vb.w;
                *(bf16x8*)&dst[i * 8] = ob;
            }
        }
    }
}

// ctx = bf16( sum_sp Opart / sum_sp lpart ); one bf16x8 slot per thread
__global__ __launch_bounds__(256)
void attn_merge_kernel(const bf16_t* __restrict__ Opart, const float* __restrict__ lpart,
                       bf16_t* __restrict__ ctx) {
    int i = blockIdx.x * 256 + threadIdx.x;
    int q = i >> 5;
    int h = (i & 31) >> 3;
    float sum[8] = {};
    float lsum = 0.f;
#pragma unroll
    for (int sp = 0; sp < NSPLIT; ++sp) {
        bf16x8 v = ((const bf16x8*)Opart)[(size_t)sp * (NE * 32) + i];
#pragma unroll
        for (int j = 0; j < 8; ++j) sum[j] += (float)v[j];
        lsum += lpart[((size_t)sp * 4 + h) * NE + q];
    }
    float rl = 1.0f / lsum;
    bf16x8 c;
#pragma unroll
    for (int j = 0; j < 8; ++j) c[j] = (bf16_t)(sum[j] * rl);
    ((bf16x8*)ctx)[i] = c;
}

// ---------------------------------------------------------------------------
// LayerNorm over rows of 256: out = LN(x + y) * g + b
// XBF16/YBF16: inputs bf16. WRITE_F32/WRITE_BF16 select outputs.
// ---------------------------------------------------------------------------
template<int XBF16, int YBF16, int WRITE_F32, int WRITE_BF16>
__global__ __launch_bounds__(256)
void ln_kernel(const void* __restrict__ xv, const void* __restrict__ yv,
               const float* __restrict__ g, const float* __restrict__ b,
               float* __restrict__ outf, bf16_t* __restrict__ outb) {
    int row = blockIdx.x * 4 + (threadIdx.x >> 6);
    int l = threadIdx.x & 63;
    float x0, x1, x2, x3, y0, y1, y2, y3;
    if (XBF16) {
        bf16x4 t = ((const bf16x4*)xv)[(long)row * 64 + l];
        x0 = (float)t[0]; x1 = (float)t[1]; x2 = (float)t[2]; x3 = (float)t[3];
    } else {
        float4 t = ((const float4*)xv)[(long)row * 64 + l];
        x0 = t.x; x1 = t.y; x2 = t.z; x3 = t.w;
    }
    if (YBF16) {
        bf16x4 t = ((const bf16x4*)yv)[(long)row * 64 + l];
        y0 = (float)t[0]; y1 = (float)t[1]; y2 = (float)t[2]; y3 = (float)t[3];
    } else {
        float4 t = ((const float4*)yv)[(long)row * 64 + l];
        y0 = t.x; y1 = t.y; y2 = t.z; y3 = t.w;
    }
    float a0 = x0 + y0, a1 = x1 + y1, a2 = x2 + y2, a3 = x3 + y3;

    float s = a0 + a1 + a2 + a3;
#pragma unroll
    for (int off = 1; off < 64; off <<= 1) s += __shfl_xor(s, off);
    float mu = s * (1.0f / 256.0f);

    float d0 = a0 - mu, d1 = a1 - mu, d2 = a2 - mu, d3 = a3 - mu;
    float q = d0 * d0 + d1 * d1 + d2 * d2 + d3 * d3;
#pragma unroll
    for (int off = 1; off < 64; off <<= 1) q += __shfl_xor(q, off);
    float rs = rsqrtf(q * (1.0f / 256.0f) + 1e-5f);

    float4 gg = ((const float4*)g)[l];
    float4 bb = ((const float4*)b)[l];
    float o0 = d0 * rs * gg.x + bb.x;
    float o1 = d1 * rs * gg.y + bb.y;
    float o2 = d2 * rs * gg.z + bb.z;
    float o3 = d3 * rs * gg.w + bb.w;
    if (WRITE_F32) {
        float4 ov; ov.x = o0; ov.y = o1; ov.z = o2; ov.w = o3;
        ((float4*)&outf[(long)row * 256])[l] = ov;
    }
    if (WRITE_BF16) {
        bf16x4 ob;
        ob[0] = (bf16_t)o0; ob[1] = (bf16_t)o1; ob[2] = (bf16_t)o2; ob[3] = (bf16_t)o3;
        ((bf16x4*)&outb[(long)row * 256])[l] = ob;
    }
}

// ---------------------------------------------------------------------------
// scatter-add e rows into per-node accumulators (+counts).
// Standalone: lane t -> acc[dst*256+t] gives stride-4B coalesced atomics
// (R9 lesson: fusing into LN2 made atomics stride-16B x4 -> +19 us).
// ---------------------------------------------------------------------------
__global__ __launch_bounds__(256)
void scatter_kernel(const float* __restrict__ e, const int* __restrict__ ei,
                    float* __restrict__ acc, float* __restrict__ cnt) {
    int edge = blockIdx.x;
    int dst = ei[NE + edge];
    int t = threadIdx.x;
    atomicAdd(&acc[(long)dst * 256 + t], e[(long)edge * 256 + t]);
    if (t == 0) atomicAdd(&cnt[dst], 1.0f);
}

// ---------------------------------------------------------------------------
extern "C" void kernel_launch(void* const* d_in, const int* in_sizes, int n_in,
                              void* d_out, int out_size, void* d_ws, size_t ws_size,
                              hipStream_t stream) {
    const float* node_features = (const float*)d_in[0];
    const float* edge_features = (const float*)d_in[1];
    const float* in_proj_w  = (const float*)d_in[2];
    const float* in_proj_b  = (const float*)d_in[3];
    const float* out_proj_w = (const float*)d_in[4];
    const float* out_proj_b = (const float*)d_in[5];
    const float* mlp_w1 = (const float*)d_in[6];
    const float* mlp_b1 = (const float*)d_in[7];
    const float* mlp_w2 = (const float*)d_in[8];
    const float* mlp_b2 = (const float*)d_in[9];
    const float* nu_w   = (const float*)d_in[10];
    const float* nu_b   = (const float*)d_in[11];
    const float* ln1_g  = (const float*)d_in[12];
    const float* ln1_b  = (const float*)d_in[13];
    const float* ln2_g  = (const float*)d_in[14];
    const float* ln2_b  = (const float*)d_in[15];
    const int*   edge_index = (const int*)d_in[16];

    char* ws = (char*)d_ws;
    size_t off = 0;
    auto alloc = [&](size_t bytes) {
        char* p = ws + off;
        off = (off + bytes + 255) & ~(size_t)255;
        return p;
    };
    // region A: persistent across the whole launch
    bf16_t* ebf   = (bf16_t*)alloc(NE * HH * 2);
    bf16_t* bwq   = (bf16_t*)alloc(768 * 256 * 2);
    bf16_t* bwo   = (bf16_t*)alloc(256 * 256 * 2);
    bf16_t* bw1   = (bf16_t*)alloc(256 * 256 * 2);
    bf16_t* bw2   = (bf16_t*)alloc(256 * 256 * 2);
    bf16_t* bwn   = (bf16_t*)alloc(256 * 256 * 2);
    bf16_t* qkv   = (bf16_t*)alloc((size_t)NE * 768 * 2);
    bf16_t* ctx   = (bf16_t*)alloc((size_t)NE * HH * 2);
    float*  lpart = (float*)alloc((size_t)NSPLIT * 4 * NE * 4);
    float*  acc   = (float*)alloc((size_t)(NN * HH + NN) * 4);
    float*  cnt   = acc + (size_t)NN * HH;
    // region B: Opart dies at merge; post-attention activations born after
    size_t offB = off;
    bf16_t* Opart = (bf16_t*)alloc((size_t)NSPLIT * NE * HH * 2);   // 16.8 MB bf16
    off = offB;
    bf16_t* attended = (bf16_t*)alloc((size_t)NE * HH * 2);
    bf16_t* e1b   = (bf16_t*)alloc((size_t)NE * HH * 2);
    bf16_t* hbuf  = (bf16_t*)alloc((size_t)NE * HH * 2);
    bf16_t* mlpout = (bf16_t*)alloc((size_t)NE * HH * 2);

    float* nout = (float*)d_out;
    float* eout = (float*)d_out + (size_t)NN * HH;

    convert_kernel<<<2048, 256, 0, stream>>>(edge_features, in_proj_w, out_proj_w,
                                             mlp_w1, mlp_w2, nu_w,
                                             ebf, bwq, bwo, bw1, bw2, bwn);

    // zero node accumulators (overlaps with the GEMMs upstream of scatter)
    hipMemsetAsync(acc, 0, (size_t)(NN * HH + NN) * 4, stream);

    // qkv = ebf @ in_proj_w^T + b -> bf16 [NE,768]; Q cols pre-scaled
    gemm_kernel<0, 1, 1, 0><<<dim3(NE / 64, 768 / 64), 256, 0, stream>>>(
        ebf, bwq, in_proj_b, qkv, nullptr, nullptr, NE, 768, 256);

    attn_kernel<<<dim3(128, NSPLIT), 256, 0, stream>>>(qkv, Opart, lpart);
    attn_merge_kernel<<<1024, 256, 0, stream>>>(Opart, lpart, ctx);

    // attended = ctx @ out_proj_w^T + b -> bf16 (read once by LN1)
    gemm_kernel<0, 1, 0, 0><<<dim3(NE / 64, 256 / 64), 256, 0, stream>>>(
        ctx, bwo, out_proj_b, attended, nullptr, nullptr, NE, 256, 256);

    // e1 = LN(edge_features + attended) -> e1b bf16 only
    ln_kernel<0, 1, 0, 1><<<NE / 4, 256, 0, stream>>>(
        edge_features, attended, ln1_g, ln1_b, nullptr, e1b);

    // h = relu(e1 @ w1^T + b1) -> bf16
    gemm_kernel<1, 1, 0, 0><<<dim3(NE / 64, 256 / 64), 256, 0, stream>>>(
        e1b, bw1, mlp_b1, hbuf, nullptr, nullptr, NE, 256, 256);

    // mlpout = h @ w2^T + b2 -> bf16 (read once by LN2)
    gemm_kernel<0, 1, 0, 0><<<dim3(NE / 64, 256 / 64), 256, 0, stream>>>(
        hbuf, bw2, mlp_b2, mlpout, nullptr, nullptr, NE, 256, 256);

    // e = LN(e1 + mlpout) -> d_out (second output)
    ln_kernel<1, 1, 1, 0><<<NE / 4, 256, 0, stream>>>(
        e1b, mlpout, ln2_g, ln2_b, eout, nullptr);

    // scatter mean (divide fused into the node GEMM's A staging)
    scatter_kernel<<<NE, 256, 0, stream>>>(eout, edge_index, acc, cnt);

    // n = node_features + relu((acc/cnt) @ nu_w^T + nu_b) -> d_out (first output)
    gemm_kernel<0, 2, 0, 1><<<dim3(NN / 64, 256 / 64), 256, 0, stream>>>(
        acc, bwn, nu_b, nout, node_features, cnt, NN, 256, 256);
}

// Round 12
// 141.979 us; speedup vs baseline: 1.1426x; 1.0112x over previous
//
#include <hip/hip_runtime.h>

typedef __bf16 bf16_t;
typedef __bf16 bf16x8 __attribute__((ext_vector_type(8)));
typedef __bf16 bf16x4 __attribute__((ext_vector_type(4)));
typedef unsigned short u16x8 __attribute__((ext_vector_type(8)));
typedef unsigned int u32x4 __attribute__((ext_vector_type(4)));
typedef float f32x4 __attribute__((ext_vector_type(4)));
typedef float f32x16 __attribute__((ext_vector_type(16)));
typedef int i32x2 __attribute__((ext_vector_type(2)));

#define NE 8192
#define NN 2048
#define HH 256
#define NSPLIT 4
// 0.125 * log2(e): folded into Q so P = exp2(S)
#define QSCALE 0.18033688011112042f

#if __has_builtin(__builtin_amdgcn_exp2f)
#define EXP2(x) __builtin_amdgcn_exp2f(x)
#else
#define EXP2(x) exp2f(x)
#endif

__device__ inline f32x4 mfma16(bf16x8 a, bf16x8 b, f32x4 c) {
    return __builtin_amdgcn_mfma_f32_16x16x32_bf16(a, b, c, 0, 0, 0);
}
__device__ inline f32x16 mfma32(bf16x8 a, bf16x8 b, f32x16 c) {
    return __builtin_amdgcn_mfma_f32_32x32x16_bf16(a, b, c, 0, 0, 0);
}
__device__ inline unsigned cvtpk(float lo, float hi) {
    unsigned r;
    asm("v_cvt_pk_bf16_f32 %0, %1, %2" : "=v"(r) : "v"(lo), "v"(hi));
    return r;
}
__device__ inline bf16x8 cvt8(float4 a, float4 b) {
    bf16x8 o;
    o[0] = (bf16_t)a.x; o[1] = (bf16_t)a.y; o[2] = (bf16_t)a.z; o[3] = (bf16_t)a.w;
    o[4] = (bf16_t)b.x; o[5] = (bf16_t)b.y; o[6] = (bf16_t)b.z; o[7] = (bf16_t)b.w;
    return o;
}
__device__ inline bf16x4 cvt4(float4 v) {
    bf16x4 o;
    o[0] = (bf16_t)v.x; o[1] = (bf16_t)v.y; o[2] = (bf16_t)v.z; o[3] = (bf16_t)v.w;
    return o;
}

// ---------------------------------------------------------------------------
// convert fp32 -> bf16: edge_features + 5 weight matrices (one pass).
// ---------------------------------------------------------------------------
__global__ __launch_bounds__(256)
void convert_kernel(const float* __restrict__ ef, const float* __restrict__ wq,
                    const float* __restrict__ wo, const float* __restrict__ w1,
                    const float* __restrict__ w2, const float* __restrict__ wn,
                    bf16_t* __restrict__ ebf, bf16_t* __restrict__ bwq,
                    bf16_t* __restrict__ bwo, bf16_t* __restrict__ bw1,
                    bf16_t* __restrict__ bw2, bf16_t* __restrict__ bwn) {
    int i = blockIdx.x * 256 + threadIdx.x;   // 0 .. 524287
    ((bf16x4*)ebf)[i] = cvt4(((const float4*)ef)[i]);
    if (i < 49152) ((bf16x4*)bwq)[i] = cvt4(((const float4*)wq)[i]);
    if (i < 16384) {
        ((bf16x4*)bwo)[i] = cvt4(((const float4*)wo)[i]);
        ((bf16x4*)bw1)[i] = cvt4(((const float4*)w1)[i]);
        ((bf16x4*)bw2)[i] = cvt4(((const float4*)w2)[i]);
        ((bf16x4*)bwn)[i] = cvt4(((const float4*)wn)[i]);
    }
}

// ---------------------------------------------------------------------------
// Generic bf16 GEMM: C = act(A * B^T + bias)  [A: MxK, B: NxK row-major bf16]
// 64x64 tile, BK=64, 256 threads (4 waves, each a 32x32 quadrant)
// QSC: scale cols<256 by QSCALE (folds attention 1/sqrt(d)*log2e into Q)
// ADIV: A is fp32, each row scaled by 1/max(cnt[row],1) during staging
//       (fuses the scatter-mean divide; A read exactly once -> fusion is free).
// ---------------------------------------------------------------------------
template<int ACT, int OUTKIND, int QSC, int ADIV>
__global__ __launch_bounds__(256)
void gemm_kernel(const void* __restrict__ Av, const bf16_t* __restrict__ B,
                 const float* __restrict__ bias, void* __restrict__ out,
                 const float* __restrict__ resid, const float* __restrict__ cntp,
                 int M, int N, int K) {
    __shared__ bf16_t As[64][72];
    __shared__ bf16_t Bs[64][72];
    int tid = threadIdx.x;
    int w = tid >> 6, l = tid & 63, hi = l >> 4, c15 = l & 15;
    int wr = w >> 1, wc = w & 1;
    int brow = blockIdx.x * 64, bcol = blockIdx.y * 64;
    int r = tid >> 2, s = tid & 3;

    f32x4 acc[2][2] = {};

    for (int k0 = 0; k0 < K; k0 += 64) {
        __syncthreads();
        if (ADIV) {
            const float* Af = (const float*)Av;
            const float* p = &Af[(long)(brow + r) * K + k0 + s * 16];
            float4 f0 = *(const float4*)p,       f1 = *(const float4*)(p + 4);
            float4 f2 = *(const float4*)(p + 8), f3 = *(const float4*)(p + 12);
            float rc = 1.0f / fmaxf(cntp[brow + r], 1.0f);
            f0.x *= rc; f0.y *= rc; f0.z *= rc; f0.w *= rc;
            f1.x *= rc; f1.y *= rc; f1.z *= rc; f1.w *= rc;
            f2.x *= rc; f2.y *= rc; f2.z *= rc; f2.w *= rc;
            f3.x *= rc; f3.y *= rc; f3.z *= rc; f3.w *= rc;
            *(bf16x8*)&As[r][s * 16]     = cvt8(f0, f1);
            *(bf16x8*)&As[r][s * 16 + 8] = cvt8(f2, f3);
        } else {
            const bf16_t* Ab = (const bf16_t*)Av;
            *(bf16x8*)&As[r][s * 16]     = *(const bf16x8*)&Ab[(long)(brow + r) * K + k0 + s * 16];
            *(bf16x8*)&As[r][s * 16 + 8] = *(const bf16x8*)&Ab[(long)(brow + r) * K + k0 + s * 16 + 8];
        }
        *(bf16x8*)&Bs[r][s * 16]     = *(const bf16x8*)&B[(long)(bcol + r) * K + k0 + s * 16];
        *(bf16x8*)&Bs[r][s * 16 + 8] = *(const bf16x8*)&B[(long)(bcol + r) * K + k0 + s * 16 + 8];
        __syncthreads();
#pragma unroll
        for (int c = 0; c < 2; ++c) {
            bf16x8 af0 = *(const bf16x8*)&As[wr * 32 + c15][c * 32 + hi * 8];
            bf16x8 af1 = *(const bf16x8*)&As[wr * 32 + 16 + c15][c * 32 + hi * 8];
            bf16x8 bf0 = *(const bf16x8*)&Bs[wc * 32 + c15][c * 32 + hi * 8];
            bf16x8 bf1 = *(const bf16x8*)&Bs[wc * 32 + 16 + c15][c * 32 + hi * 8];
            acc[0][0] = mfma16(af0, bf0, acc[0][0]);
            acc[0][1] = mfma16(af0, bf1, acc[0][1]);
            acc[1][0] = mfma16(af1, bf0, acc[1][0]);
            acc[1][1] = mfma16(af1, bf1, acc[1][1]);
        }
    }

    float sc = (QSC && bcol < 256) ? QSCALE : 1.0f;
#pragma unroll
    for (int i = 0; i < 2; ++i)
#pragma unroll
        for (int j = 0; j < 2; ++j)
#pragma unroll
            for (int rg = 0; rg < 4; ++rg) {
                int row = brow + wr * 32 + i * 16 + hi * 4 + rg;
                int col = bcol + wc * 32 + j * 16 + c15;
                float v = (acc[i][j][rg] + bias[col]) * sc;
                if (ACT) v = fmaxf(v, 0.0f);
                if (OUTKIND == 0) {
                    ((float*)out)[(long)row * N + col] = v;
                } else if (OUTKIND == 1) {
                    ((bf16_t*)out)[(long)row * N + col] = (bf16_t)v;
                } else {
                    ((float*)out)[(long)row * N + col] =
                        resid[(long)row * N + col] + fmaxf(v, 0.0f);
                }
            }
}

// ---------------------------------------------------------------------------
// Flash attention, 32x32x16 MFMA, swapped QK^T (S^T = K Q^T): softmax is
// lane-local, P feeds PV's B-operand via cvt_pk + permlane32_swap (no LDS).
// Q pre-scaled by 0.125*log2e so P = exp2(S).
// Block: 256 thr = 4 waves, each wave 64 q-rows (2 qt sub-tiles) -> q-block 256.
// grid = dim3(128, NSPLIT=4) = 512 blocks = exactly 2 blocks/CU — matches the
// register-file residency cap. S-init uses a persistent zero f32x16 as the
// MFMA C-operand (kills ~64 v_mov/tile of re-zeroing; VGPR 128->~144, still
// far under the (256,2) cap of 256).
// NO s_setprio (R6: fences the scheduler here, -9 us).
// ---------------------------------------------------------------------------
__global__ __launch_bounds__(256, 2)
void attn_kernel(const bf16_t* __restrict__ qkv, bf16_t* __restrict__ Opart,
                 float* __restrict__ lpart) {
    __shared__ char smem[36864];
    bf16_t (*Ks)[64][72] = (bf16_t (*)[64][72])smem;             // [buf][kv][d]
    bf16_t (*Vt)[64][72] = (bf16_t (*)[64][72])(smem + 18432);   // [buf][d][kv]

    int h = blockIdx.x & 3, qb = blockIdx.x >> 2, sp = blockIdx.y;
    int q0 = qb * 256;
    int tid = threadIdx.x;
    int wv = tid >> 6, l = tid & 63, l31 = l & 31, h8 = l >> 5;

    bf16x8 qf[2][4];
#pragma unroll
    for (int qt = 0; qt < 2; ++qt)
#pragma unroll
        for (int dc = 0; dc < 4; ++dc)
            qf[qt][dc] = *(const bf16x8*)&qkv[
                (size_t)(q0 + wv * 64 + qt * 32 + l31) * 768 + h * 64 + dc * 16 + h8 * 8];

    f32x16 o[2][2];
#pragma unroll
    for (int a = 0; a < 2; ++a)
#pragma unroll
        for (int b = 0; b < 2; ++b)
#pragma unroll
            for (int r = 0; r < 16; ++r) o[a][b][r] = 0.f;
    float ls[2] = {0.f, 0.f};

    // persistent zero C-operand for the S MFMA chain
    f32x16 z16;
#pragma unroll
    for (int r = 0; r < 16; ++r) z16[r] = 0.f;

    int kr = tid >> 2, ksc = tid & 3;
    int vp = tid & 31, vc = tid >> 5;
    int kv0 = sp * (NE / NSPLIT);
    const int NT = (NE / NSPLIT) / 64;

    bf16x8 kst0, kst1, vst0, vst1;
    {
        const bf16_t* ksrc = &qkv[(size_t)(kv0 + kr) * 768 + 256 + h * 64 + ksc * 16];
        kst0 = *(const bf16x8*)ksrc; kst1 = *(const bf16x8*)(ksrc + 8);
        const bf16_t* vsrc = &qkv[(size_t)(kv0 + 2 * vp) * 768 + 512 + h * 64 + vc * 8];
        vst0 = *(const bf16x8*)vsrc; vst1 = *(const bf16x8*)(vsrc + 768);
    }
    {
        *(bf16x8*)&Ks[0][kr][ksc * 16]     = kst0;
        *(bf16x8*)&Ks[0][kr][ksc * 16 + 8] = kst1;
        u16x8 ua = __builtin_bit_cast(u16x8, vst0), ub = __builtin_bit_cast(u16x8, vst1);
#pragma unroll
        for (int j = 0; j < 8; ++j) {
            unsigned wd = (unsigned)ua[j] | ((unsigned)ub[j] << 16);
            *(unsigned*)&Vt[0][vc * 8 + j][2 * vp] = wd;
        }
    }

    for (int t = 0; t < NT; ++t) {
        int cur = t & 1;
        __syncthreads();
        if (t + 1 < NT) {
            int kt = kv0 + (t + 1) * 64;
            const bf16_t* ksrc = &qkv[(size_t)(kt + kr) * 768 + 256 + h * 64 + ksc * 16];
            kst0 = *(const bf16x8*)ksrc; kst1 = *(const bf16x8*)(ksrc + 8);
            const bf16_t* vsrc = &qkv[(size_t)(kt + 2 * vp) * 768 + 512 + h * 64 + vc * 8];
            vst0 = *(const bf16x8*)vsrc; vst1 = *(const bf16x8*)(vsrc + 768);
        }

#pragma unroll
        for (int kvt = 0; kvt < 2; ++kvt) {
            bf16x8 kf[4];
#pragma unroll
            for (int dc = 0; dc < 4; ++dc)
                kf[dc] = *(const bf16x8*)&Ks[cur][kvt * 32 + l31][dc * 16 + h8 * 8];
            f32x16 s[2];
#pragma unroll
            for (int qt = 0; qt < 2; ++qt) {
                s[qt] = mfma32(kf[0], qf[qt][0], z16);
#pragma unroll
                for (int dc = 1; dc < 4; ++dc)
                    s[qt] = mfma32(kf[dc], qf[qt][dc], s[qt]);
            }
            bf16x8 bfr[2][2];
#pragma unroll
            for (int qt = 0; qt < 2; ++qt) {
                float p[16];
#pragma unroll
                for (int r = 0; r < 16; ++r) { p[r] = EXP2(s[qt][r]); ls[qt] += p[r]; }
#pragma unroll
                for (int half = 0; half < 2; ++half) {
                    i32x2 r0 = __builtin_amdgcn_permlane32_swap(
                        (int)cvtpk(p[8 * half + 0], p[8 * half + 1]),
                        (int)cvtpk(p[8 * half + 4], p[8 * half + 5]), false, false);
                    i32x2 r1 = __builtin_amdgcn_permlane32_swap(
                        (int)cvtpk(p[8 * half + 2], p[8 * half + 3]),
                        (int)cvtpk(p[8 * half + 6], p[8 * half + 7]), false, false);
                    u32x4 wds;
                    wds[0] = (unsigned)r0[0]; wds[1] = (unsigned)r1[0];
                    wds[2] = (unsigned)r0[1]; wds[3] = (unsigned)r1[1];
                    bfr[qt][half] = __builtin_bit_cast(bf16x8, wds);
                }
            }
#pragma unroll
            for (int dt = 0; dt < 2; ++dt) {
                bf16x8 vf[2];
#pragma unroll
                for (int half = 0; half < 2; ++half)
                    vf[half] = *(const bf16x8*)&Vt[cur][dt * 32 + l31][(kvt * 2 + half) * 16 + h8 * 8];
#pragma unroll
                for (int qt = 0; qt < 2; ++qt)
#pragma unroll
                    for (int half = 0; half < 2; ++half)
                        o[dt][qt] = mfma32(vf[half], bfr[qt][half], o[dt][qt]);
            }
        }

        if (t + 1 < NT) {
            int nb = (t + 1) & 1;
            *(bf16x8*)&Ks[nb][kr][ksc * 16]     = kst0;
            *(bf16x8*)&Ks[nb][kr][ksc * 16 + 8] = kst1;
            u16x8 ua = __builtin_bit_cast(u16x8, vst0), ub = __builtin_bit_cast(u16x8, vst1);
#pragma unroll
            for (int j = 0; j < 8; ++j) {
                unsigned wd = (unsigned)ua[j] | ((unsigned)ub[j] << 16);
                *(unsigned*)&Vt[nb][vc * 8 + j][2 * vp] = wd;
            }
        }
    }

#pragma unroll
    for (int qt = 0; qt < 2; ++qt) {
        float lt = ls[qt] + __shfl_xor(ls[qt], 32);
        if (l < 32)
            lpart[((size_t)sp * 4 + h) * NE + q0 + wv * 64 + qt * 32 + l31] = lt;
    }

    float* Of = (float*)smem;
#pragma unroll
    for (int pass = 0; pass < 2; ++pass) {
        __syncthreads();
        if ((wv >> 1) == pass) {
#pragma unroll
            for (int dt = 0; dt < 2; ++dt)
#pragma unroll
                for (int qt = 0; qt < 2; ++qt)
#pragma unroll
                    for (int r = 0; r < 16; ++r) {
                        int qrel = (wv & 1) * 64 + qt * 32 + l31;
                        int d = dt * 32 + (r & 3) + 8 * (r >> 2) + 4 * h8;
                        Of[qrel * 68 + d] = o[dt][qt][r];
                    }
        }
        __syncthreads();
        {
            int rr = tid >> 1, hf = tid & 1;
            bf16_t* dst = &Opart[(size_t)sp * NE * 256 +
                                 (size_t)(q0 + pass * 128 + rr) * 256 + h * 64 + hf * 32];
#pragma unroll
            for (int i = 0; i < 4; ++i) {
                float4 va = *(float4*)&Of[rr * 68 + hf * 32 + i * 8];
                float4 vb = *(float4*)&Of[rr * 68 + hf * 32 + i * 8 + 4];
                bf16x8 ob;
                ob[0] = (bf16_t)va.x; ob[1] = (bf16_t)va.y;
                ob[2] = (bf16_t)va.z; ob[3] = (bf16_t)va.w;
                ob[4] = (bf16_t)vb.x; ob[5] = (bf16_t)vb.y;
                ob[6] = (bf16_t)vb.z; ob[7] = (bf16_t)vb.w;
                *(bf16x8*)&dst[i * 8] = ob;
            }
        }
    }
}

// ctx = bf16( sum_sp Opart / sum_sp lpart ); one bf16x8 slot per thread
__global__ __launch_bounds__(256)
void attn_merge_kernel(const bf16_t* __restrict__ Opart, const float* __restrict__ lpart,
                       bf16_t* __restrict__ ctx) {
    int i = blockIdx.x * 256 + threadIdx.x;
    int q = i >> 5;
    int h = (i & 31) >> 3;
    float sum[8] = {};
    float lsum = 0.f;
#pragma unroll
    for (int sp = 0; sp < NSPLIT; ++sp) {
        bf16x8 v = ((const bf16x8*)Opart)[(size_t)sp * (NE * 32) + i];
#pragma unroll
        for (int j = 0; j < 8; ++j) sum[j] += (float)v[j];
        lsum += lpart[((size_t)sp * 4 + h) * NE + q];
    }
    float rl = 1.0f / lsum;
    bf16x8 c;
#pragma unroll
    for (int j = 0; j < 8; ++j) c[j] = (bf16_t)(sum[j] * rl);
    ((bf16x8*)ctx)[i] = c;
}

// ---------------------------------------------------------------------------
// LayerNorm over rows of 256: out = LN(x + y) * g + b
// XBF16/YBF16: inputs bf16. WRITE_F32/WRITE_BF16 select outputs.
// SCATTER: fused coalesced scatter — outputs are transposed through LDS so
// thread t atomically adds column t of each of the block's 4 rows
// (acc[dst*256+t] consecutive across the wave — same pattern as the old
// standalone scatter; R9's slow version had lane-strided atomics).
// ---------------------------------------------------------------------------
template<int XBF16, int YBF16, int WRITE_F32, int WRITE_BF16, int SCATTER>
__global__ __launch_bounds__(256)
void ln_kernel(const void* __restrict__ xv, const void* __restrict__ yv,
               const float* __restrict__ g, const float* __restrict__ b,
               float* __restrict__ outf, bf16_t* __restrict__ outb,
               const int* __restrict__ ei, float* __restrict__ acc,
               float* __restrict__ cnt) {
    __shared__ float sl[SCATTER ? 4 : 1][SCATTER ? 256 : 1];
    int w = threadIdx.x >> 6;
    int row = blockIdx.x * 4 + w;
    int l = threadIdx.x & 63;
    float x0, x1, x2, x3, y0, y1, y2, y3;
    if (XBF16) {
        bf16x4 t = ((const bf16x4*)xv)[(long)row * 64 + l];
        x0 = (float)t[0]; x1 = (float)t[1]; x2 = (float)t[2]; x3 = (float)t[3];
    } else {
        float4 t = ((const float4*)xv)[(long)row * 64 + l];
        x0 = t.x; x1 = t.y; x2 = t.z; x3 = t.w;
    }
    if (YBF16) {
        bf16x4 t = ((const bf16x4*)yv)[(long)row * 64 + l];
        y0 = (float)t[0]; y1 = (float)t[1]; y2 = (float)t[2]; y3 = (float)t[3];
    } else {
        float4 t = ((const float4*)yv)[(long)row * 64 + l];
        y0 = t.x; y1 = t.y; y2 = t.z; y3 = t.w;
    }
    float a0 = x0 + y0, a1 = x1 + y1, a2 = x2 + y2, a3 = x3 + y3;

    float s = a0 + a1 + a2 + a3;
#pragma unroll
    for (int off = 1; off < 64; off <<= 1) s += __shfl_xor(s, off);
    float mu = s * (1.0f / 256.0f);

    float d0 = a0 - mu, d1 = a1 - mu, d2 = a2 - mu, d3 = a3 - mu;
    float q = d0 * d0 + d1 * d1 + d2 * d2 + d3 * d3;
#pragma unroll
    for (int off = 1; off < 64; off <<= 1) q += __shfl_xor(q, off);
    float rs = rsqrtf(q * (1.0f / 256.0f) + 1e-5f);

    float4 gg = ((const float4*)g)[l];
    float4 bb = ((const float4*)b)[l];
    float o0 = d0 * rs * gg.x + bb.x;
    float o1 = d1 * rs * gg.y + bb.y;
    float o2 = d2 * rs * gg.z + bb.z;
    float o3 = d3 * rs * gg.w + bb.w;
    if (WRITE_F32) {
        float4 ov; ov.x = o0; ov.y = o1; ov.z = o2; ov.w = o3;
        ((float4*)&outf[(long)row * 256])[l] = ov;
    }
    if (WRITE_BF16) {
        bf16x4 ob;
        ob[0] = (bf16_t)o0; ob[1] = (bf16_t)o1; ob[2] = (bf16_t)o2; ob[3] = (bf16_t)o3;
        ((bf16x4*)&outb[(long)row * 256])[l] = ob;
    }
    if (SCATTER) {
        sl[w][l * 4 + 0] = o0; sl[w][l * 4 + 1] = o1;
        sl[w][l * 4 + 2] = o2; sl[w][l * 4 + 3] = o3;
        __syncthreads();
        int t = threadIdx.x;
#pragma unroll
        for (int r = 0; r < 4; ++r) {
            int dst = ei[NE + blockIdx.x * 4 + r];
            atomicAdd(&acc[(long)dst * 256 + t], sl[r][t]);
        }
        if (t < 4) atomicAdd(&cnt[ei[NE + blockIdx.x * 4 + t]], 1.0f);
    }
}

// ---------------------------------------------------------------------------
extern "C" void kernel_launch(void* const* d_in, const int* in_sizes, int n_in,
                              void* d_out, int out_size, void* d_ws, size_t ws_size,
                              hipStream_t stream) {
    const float* node_features = (const float*)d_in[0];
    const float* edge_features = (const float*)d_in[1];
    const float* in_proj_w  = (const float*)d_in[2];
    const float* in_proj_b  = (const float*)d_in[3];
    const float* out_proj_w = (const float*)d_in[4];
    const float* out_proj_b = (const float*)d_in[5];
    const float* mlp_w1 = (const float*)d_in[6];
    const float* mlp_b1 = (const float*)d_in[7];
    const float* mlp_w2 = (const float*)d_in[8];
    const float* mlp_b2 = (const float*)d_in[9];
    const float* nu_w   = (const float*)d_in[10];
    const float* nu_b   = (const float*)d_in[11];
    const float* ln1_g  = (const float*)d_in[12];
    const float* ln1_b  = (const float*)d_in[13];
    const float* ln2_g  = (const float*)d_in[14];
    const float* ln2_b  = (const float*)d_in[15];
    const int*   edge_index = (const int*)d_in[16];

    char* ws = (char*)d_ws;
    size_t off = 0;
    auto alloc = [&](size_t bytes) {
        char* p = ws + off;
        off = (off + bytes + 255) & ~(size_t)255;
        return p;
    };
    // region A: persistent across the whole launch
    bf16_t* ebf   = (bf16_t*)alloc(NE * HH * 2);
    bf16_t* bwq   = (bf16_t*)alloc(768 * 256 * 2);
    bf16_t* bwo   = (bf16_t*)alloc(256 * 256 * 2);
    bf16_t* bw1   = (bf16_t*)alloc(256 * 256 * 2);
    bf16_t* bw2   = (bf16_t*)alloc(256 * 256 * 2);
    bf16_t* bwn   = (bf16_t*)alloc(256 * 256 * 2);
    bf16_t* qkv   = (bf16_t*)alloc((size_t)NE * 768 * 2);
    bf16_t* ctx   = (bf16_t*)alloc((size_t)NE * HH * 2);
    float*  lpart = (float*)alloc((size_t)NSPLIT * 4 * NE * 4);
    float*  acc   = (float*)alloc((size_t)(NN * HH + NN) * 4);
    float*  cnt   = acc + (size_t)NN * HH;
    // region B: Opart dies at merge; post-attention activations born after
    size_t offB = off;
    bf16_t* Opart = (bf16_t*)alloc((size_t)NSPLIT * NE * HH * 2);   // 16.8 MB bf16
    off = offB;
    bf16_t* attended = (bf16_t*)alloc((size_t)NE * HH * 2);
    bf16_t* e1b   = (bf16_t*)alloc((size_t)NE * HH * 2);
    bf16_t* hbuf  = (bf16_t*)alloc((size_t)NE * HH * 2);
    bf16_t* mlpout = (bf16_t*)alloc((size_t)NE * HH * 2);

    float* nout = (float*)d_out;
    float* eout = (float*)d_out + (size_t)NN * HH;

    convert_kernel<<<2048, 256, 0, stream>>>(edge_features, in_proj_w, out_proj_w,
                                             mlp_w1, mlp_w2, nu_w,
                                             ebf, bwq, bwo, bw1, bw2, bwn);

    // zero node accumulators (completes long before the fused LN2 scatter)
    hipMemsetAsync(acc, 0, (size_t)(NN * HH + NN) * 4, stream);

    // qkv = ebf @ in_proj_w^T + b -> bf16 [NE,768]; Q cols pre-scaled
    gemm_kernel<0, 1, 1, 0><<<dim3(NE / 64, 768 / 64), 256, 0, stream>>>(
        ebf, bwq, in_proj_b, qkv, nullptr, nullptr, NE, 768, 256);

    attn_kernel<<<dim3(128, NSPLIT), 256, 0, stream>>>(qkv, Opart, lpart);
    attn_merge_kernel<<<1024, 256, 0, stream>>>(Opart, lpart, ctx);

    // attended = ctx @ out_proj_w^T + b -> bf16 (read once by LN1)
    gemm_kernel<0, 1, 0, 0><<<dim3(NE / 64, 256 / 64), 256, 0, stream>>>(
        ctx, bwo, out_proj_b, attended, nullptr, nullptr, NE, 256, 256);

    // e1 = LN(edge_features + attended) -> e1b bf16 only
    ln_kernel<0, 1, 0, 1, 0><<<NE / 4, 256, 0, stream>>>(
        edge_features, attended, ln1_g, ln1_b, nullptr, e1b,
        nullptr, nullptr, nullptr);

    // h = relu(e1 @ w1^T + b1) -> bf16
    gemm_kernel<1, 1, 0, 0><<<dim3(NE / 64, 256 / 64), 256, 0, stream>>>(
        e1b, bw1, mlp_b1, hbuf, nullptr, nullptr, NE, 256, 256);

    // mlpout = h @ w2^T + b2 -> bf16 (read once by LN2)
    gemm_kernel<0, 1, 0, 0><<<dim3(NE / 64, 256 / 64), 256, 0, stream>>>(
        hbuf, bw2, mlp_b2, mlpout, nullptr, nullptr, NE, 256, 256);

    // e = LN(e1 + mlpout) -> d_out (second output) + fused coalesced scatter
    ln_kernel<1, 1, 1, 0, 1><<<NE / 4, 256, 0, stream>>>(
        e1b, mlpout, ln2_g, ln2_b, eout, nullptr,
        edge_index, acc, cnt);

    // n = node_features + relu((acc/cnt) @ nu_w^T + nu_b) -> d_out (first output)
    gemm_kernel<0, 2, 0, 1><<<dim3(NN / 64, 256 / 64), 256, 0, stream>>>(
        acc, bwn, nu_b, nout, node_features, cnt, NN, 256, 256);
}

// Round 13
// 137.344 us; speedup vs baseline: 1.1811x; 1.0337x over previous
//
#include <hip/hip_runtime.h>

typedef __bf16 bf16_t;
typedef __bf16 bf16x8 __attribute__((ext_vector_type(8)));
typedef __bf16 bf16x4 __attribute__((ext_vector_type(4)));
typedef unsigned short u16x8 __attribute__((ext_vector_type(8)));
typedef unsigned int u32x4 __attribute__((ext_vector_type(4)));
typedef float f32x4 __attribute__((ext_vector_type(4)));
typedef float f32x16 __attribute__((ext_vector_type(16)));
typedef int i32x2 __attribute__((ext_vector_type(2)));

#define NE 8192
#define NN 2048
#define HH 256
#define NSPLIT 4
// 0.125 * log2(e): folded into Q so P = exp2(S)
#define QSCALE 0.18033688011112042f

#if __has_builtin(__builtin_amdgcn_exp2f)
#define EXP2(x) __builtin_amdgcn_exp2f(x)
#else
#define EXP2(x) exp2f(x)
#endif

__device__ inline f32x4 mfma16(bf16x8 a, bf16x8 b, f32x4 c) {
    return __builtin_amdgcn_mfma_f32_16x16x32_bf16(a, b, c, 0, 0, 0);
}
__device__ inline f32x16 mfma32(bf16x8 a, bf16x8 b, f32x16 c) {
    return __builtin_amdgcn_mfma_f32_32x32x16_bf16(a, b, c, 0, 0, 0);
}
__device__ inline unsigned cvtpk(float lo, float hi) {
    unsigned r;
    asm("v_cvt_pk_bf16_f32 %0, %1, %2" : "=v"(r) : "v"(lo), "v"(hi));
    return r;
}
__device__ inline bf16x8 cvt8(float4 a, float4 b) {
    bf16x8 o;
    o[0] = (bf16_t)a.x; o[1] = (bf16_t)a.y; o[2] = (bf16_t)a.z; o[3] = (bf16_t)a.w;
    o[4] = (bf16_t)b.x; o[5] = (bf16_t)b.y; o[6] = (bf16_t)b.z; o[7] = (bf16_t)b.w;
    return o;
}
__device__ inline bf16x4 cvt4(float4 v) {
    bf16x4 o;
    o[0] = (bf16_t)v.x; o[1] = (bf16_t)v.y; o[2] = (bf16_t)v.z; o[3] = (bf16_t)v.w;
    return o;
}

// ---------------------------------------------------------------------------
// convert fp32 -> bf16: edge_features + 5 weight matrices (one pass).
// ---------------------------------------------------------------------------
__global__ __launch_bounds__(256)
void convert_kernel(const float* __restrict__ ef, const float* __restrict__ wq,
                    const float* __restrict__ wo, const float* __restrict__ w1,
                    const float* __restrict__ w2, const float* __restrict__ wn,
                    bf16_t* __restrict__ ebf, bf16_t* __restrict__ bwq,
                    bf16_t* __restrict__ bwo, bf16_t* __restrict__ bw1,
                    bf16_t* __restrict__ bw2, bf16_t* __restrict__ bwn) {
    int i = blockIdx.x * 256 + threadIdx.x;   // 0 .. 524287
    ((bf16x4*)ebf)[i] = cvt4(((const float4*)ef)[i]);
    if (i < 49152) ((bf16x4*)bwq)[i] = cvt4(((const float4*)wq)[i]);
    if (i < 16384) {
        ((bf16x4*)bwo)[i] = cvt4(((const float4*)wo)[i]);
        ((bf16x4*)bw1)[i] = cvt4(((const float4*)w1)[i]);
        ((bf16x4*)bw2)[i] = cvt4(((const float4*)w2)[i]);
        ((bf16x4*)bwn)[i] = cvt4(((const float4*)wn)[i]);
    }
}

// ---------------------------------------------------------------------------
// Generic bf16 GEMM: C = act(A * B^T + bias)  [A: MxK, B: NxK row-major bf16]
// 64x64 tile, BK=64, 256 threads (4 waves, each a 32x32 quadrant)
// QSC: scale cols<256 by QSCALE (folds attention 1/sqrt(d)*log2e into Q)
// ADIV: A is fp32, each row scaled by 1/max(cnt[row],1) during staging.
// AMERGE: A is the attention split-partials Opart [NSPLIT][M][256] bf16 +
//   lprt [NSPLIT][4][M] row-sums; staging computes sum_sp(Opart)/sum_sp(l)
//   (h = k0>>6 constant per k-step). Fuses attn_merge into the GEMM — kills
//   a dispatch + the ctx round-trip; A re-read only 4x (N=256), all L3-hot.
// ---------------------------------------------------------------------------
template<int ACT, int OUTKIND, int QSC, int ADIV, int AMERGE>
__global__ __launch_bounds__(256)
void gemm_kernel(const void* __restrict__ Av, const bf16_t* __restrict__ B,
                 const float* __restrict__ bias, void* __restrict__ out,
                 const float* __restrict__ resid, const float* __restrict__ cntp,
                 const float* __restrict__ lprt, int M, int N, int K) {
    __shared__ bf16_t As[64][72];
    __shared__ bf16_t Bs[64][72];
    int tid = threadIdx.x;
    int w = tid >> 6, l = tid & 63, hi = l >> 4, c15 = l & 15;
    int wr = w >> 1, wc = w & 1;
    int brow = blockIdx.x * 64, bcol = blockIdx.y * 64;
    int r = tid >> 2, s = tid & 3;

    f32x4 acc[2][2] = {};

    for (int k0 = 0; k0 < K; k0 += 64) {
        __syncthreads();
        if (ADIV) {
            const float* Af = (const float*)Av;
            const float* p = &Af[(long)(brow + r) * K + k0 + s * 16];
            float4 f0 = *(const float4*)p,       f1 = *(const float4*)(p + 4);
            float4 f2 = *(const float4*)(p + 8), f3 = *(const float4*)(p + 12);
            float rc = 1.0f / fmaxf(cntp[brow + r], 1.0f);
            f0.x *= rc; f0.y *= rc; f0.z *= rc; f0.w *= rc;
            f1.x *= rc; f1.y *= rc; f1.z *= rc; f1.w *= rc;
            f2.x *= rc; f2.y *= rc; f2.z *= rc; f2.w *= rc;
            f3.x *= rc; f3.y *= rc; f3.z *= rc; f3.w *= rc;
            *(bf16x8*)&As[r][s * 16]     = cvt8(f0, f1);
            *(bf16x8*)&As[r][s * 16 + 8] = cvt8(f2, f3);
        } else if (AMERGE) {
            const bf16_t* Am = (const bf16_t*)Av;
            int q = brow + r;
            int hh = k0 >> 6;                 // head index, constant per k-step
            float lsum = 0.f;
            float sum[16] = {};
#pragma unroll
            for (int sp = 0; sp < NSPLIT; ++sp) {
                lsum += lprt[((size_t)sp * 4 + hh) * M + q];
                const bf16_t* src = &Am[((size_t)sp * M + q) * 256 + k0 + s * 16];
                bf16x8 va = *(const bf16x8*)src;
                bf16x8 vb = *(const bf16x8*)(src + 8);
#pragma unroll
                for (int j = 0; j < 8; ++j) {
                    sum[j]     += (float)va[j];
                    sum[8 + j] += (float)vb[j];
                }
            }
            float rl = 1.0f / lsum;
            bf16x8 o0, o1;
#pragma unroll
            for (int j = 0; j < 8; ++j) {
                o0[j] = (bf16_t)(sum[j] * rl);
                o1[j] = (bf16_t)(sum[8 + j] * rl);
            }
            *(bf16x8*)&As[r][s * 16]     = o0;
            *(bf16x8*)&As[r][s * 16 + 8] = o1;
        } else {
            const bf16_t* Ab = (const bf16_t*)Av;
            *(bf16x8*)&As[r][s * 16]     = *(const bf16x8*)&Ab[(long)(brow + r) * K + k0 + s * 16];
            *(bf16x8*)&As[r][s * 16 + 8] = *(const bf16x8*)&Ab[(long)(brow + r) * K + k0 + s * 16 + 8];
        }
        *(bf16x8*)&Bs[r][s * 16]     = *(const bf16x8*)&B[(long)(bcol + r) * K + k0 + s * 16];
        *(bf16x8*)&Bs[r][s * 16 + 8] = *(const bf16x8*)&B[(long)(bcol + r) * K + k0 + s * 16 + 8];
        __syncthreads();
#pragma unroll
        for (int c = 0; c < 2; ++c) {
            bf16x8 af0 = *(const bf16x8*)&As[wr * 32 + c15][c * 32 + hi * 8];
            bf16x8 af1 = *(const bf16x8*)&As[wr * 32 + 16 + c15][c * 32 + hi * 8];
            bf16x8 bf0 = *(const bf16x8*)&Bs[wc * 32 + c15][c * 32 + hi * 8];
            bf16x8 bf1 = *(const bf16x8*)&Bs[wc * 32 + 16 + c15][c * 32 + hi * 8];
            acc[0][0] = mfma16(af0, bf0, acc[0][0]);
            acc[0][1] = mfma16(af0, bf1, acc[0][1]);
            acc[1][0] = mfma16(af1, bf0, acc[1][0]);
            acc[1][1] = mfma16(af1, bf1, acc[1][1]);
        }
    }

    float sc = (QSC && bcol < 256) ? QSCALE : 1.0f;
#pragma unroll
    for (int i = 0; i < 2; ++i)
#pragma unroll
        for (int j = 0; j < 2; ++j)
#pragma unroll
            for (int rg = 0; rg < 4; ++rg) {
                int row = brow + wr * 32 + i * 16 + hi * 4 + rg;
                int col = bcol + wc * 32 + j * 16 + c15;
                float v = (acc[i][j][rg] + bias[col]) * sc;
                if (ACT) v = fmaxf(v, 0.0f);
                if (OUTKIND == 0) {
                    ((float*)out)[(long)row * N + col] = v;
                } else if (OUTKIND == 1) {
                    ((bf16_t*)out)[(long)row * N + col] = (bf16_t)v;
                } else {
                    ((float*)out)[(long)row * N + col] =
                        resid[(long)row * N + col] + fmaxf(v, 0.0f);
                }
            }
}

// ---------------------------------------------------------------------------
// Flash attention, 32x32x16 MFMA, swapped QK^T (S^T = K Q^T): softmax is
// lane-local, P feeds PV's B-operand via cvt_pk + permlane32_swap (no LDS).
// Q pre-scaled by 0.125*log2e so P = exp2(S).
// Block: 256 thr = 4 waves, each wave 64 q-rows (2 qt sub-tiles) -> q-block 256.
// grid = dim3(128, NSPLIT=4) = 512 blocks = exactly 2 blocks/CU — matches the
// register-file residency cap. NO s_setprio (R6: -9 us).
// ~921 TF effective — at the 2-barrier-structure plateau (MFMA floor 28.8 us).
// ---------------------------------------------------------------------------
__global__ __launch_bounds__(256, 2)
void attn_kernel(const bf16_t* __restrict__ qkv, bf16_t* __restrict__ Opart,
                 float* __restrict__ lpart) {
    __shared__ char smem[36864];
    bf16_t (*Ks)[64][72] = (bf16_t (*)[64][72])smem;             // [buf][kv][d]
    bf16_t (*Vt)[64][72] = (bf16_t (*)[64][72])(smem + 18432);   // [buf][d][kv]

    int h = blockIdx.x & 3, qb = blockIdx.x >> 2, sp = blockIdx.y;
    int q0 = qb * 256;
    int tid = threadIdx.x;
    int wv = tid >> 6, l = tid & 63, l31 = l & 31, h8 = l >> 5;

    bf16x8 qf[2][4];
#pragma unroll
    for (int qt = 0; qt < 2; ++qt)
#pragma unroll
        for (int dc = 0; dc < 4; ++dc)
            qf[qt][dc] = *(const bf16x8*)&qkv[
                (size_t)(q0 + wv * 64 + qt * 32 + l31) * 768 + h * 64 + dc * 16 + h8 * 8];

    f32x16 o[2][2];
#pragma unroll
    for (int a = 0; a < 2; ++a)
#pragma unroll
        for (int b = 0; b < 2; ++b)
#pragma unroll
            for (int r = 0; r < 16; ++r) o[a][b][r] = 0.f;
    float ls[2] = {0.f, 0.f};

    // persistent zero C-operand for the S MFMA chain
    f32x16 z16;
#pragma unroll
    for (int r = 0; r < 16; ++r) z16[r] = 0.f;

    int kr = tid >> 2, ksc = tid & 3;
    int vp = tid & 31, vc = tid >> 5;
    int kv0 = sp * (NE / NSPLIT);
    const int NT = (NE / NSPLIT) / 64;

    bf16x8 kst0, kst1, vst0, vst1;
    {
        const bf16_t* ksrc = &qkv[(size_t)(kv0 + kr) * 768 + 256 + h * 64 + ksc * 16];
        kst0 = *(const bf16x8*)ksrc; kst1 = *(const bf16x8*)(ksrc + 8);
        const bf16_t* vsrc = &qkv[(size_t)(kv0 + 2 * vp) * 768 + 512 + h * 64 + vc * 8];
        vst0 = *(const bf16x8*)vsrc; vst1 = *(const bf16x8*)(vsrc + 768);
    }
    {
        *(bf16x8*)&Ks[0][kr][ksc * 16]     = kst0;
        *(bf16x8*)&Ks[0][kr][ksc * 16 + 8] = kst1;
        u16x8 ua = __builtin_bit_cast(u16x8, vst0), ub = __builtin_bit_cast(u16x8, vst1);
#pragma unroll
        for (int j = 0; j < 8; ++j) {
            unsigned wd = (unsigned)ua[j] | ((unsigned)ub[j] << 16);
            *(unsigned*)&Vt[0][vc * 8 + j][2 * vp] = wd;
        }
    }

    for (int t = 0; t < NT; ++t) {
        int cur = t & 1;
        __syncthreads();
        if (t + 1 < NT) {
            int kt = kv0 + (t + 1) * 64;
            const bf16_t* ksrc = &qkv[(size_t)(kt + kr) * 768 + 256 + h * 64 + ksc * 16];
            kst0 = *(const bf16x8*)ksrc; kst1 = *(const bf16x8*)(ksrc + 8);
            const bf16_t* vsrc = &qkv[(size_t)(kt + 2 * vp) * 768 + 512 + h * 64 + vc * 8];
            vst0 = *(const bf16x8*)vsrc; vst1 = *(const bf16x8*)(vsrc + 768);
        }

#pragma unroll
        for (int kvt = 0; kvt < 2; ++kvt) {
            bf16x8 kf[4];
#pragma unroll
            for (int dc = 0; dc < 4; ++dc)
                kf[dc] = *(const bf16x8*)&Ks[cur][kvt * 32 + l31][dc * 16 + h8 * 8];
            f32x16 s[2];
#pragma unroll
            for (int qt = 0; qt < 2; ++qt) {
                s[qt] = mfma32(kf[0], qf[qt][0], z16);
#pragma unroll
                for (int dc = 1; dc < 4; ++dc)
                    s[qt] = mfma32(kf[dc], qf[qt][dc], s[qt]);
            }
            bf16x8 bfr[2][2];
#pragma unroll
            for (int qt = 0; qt < 2; ++qt) {
                float p[16];
#pragma unroll
                for (int r = 0; r < 16; ++r) { p[r] = EXP2(s[qt][r]); ls[qt] += p[r]; }
#pragma unroll
                for (int half = 0; half < 2; ++half) {
                    i32x2 r0 = __builtin_amdgcn_permlane32_swap(
                        (int)cvtpk(p[8 * half + 0], p[8 * half + 1]),
                        (int)cvtpk(p[8 * half + 4], p[8 * half + 5]), false, false);
                    i32x2 r1 = __builtin_amdgcn_permlane32_swap(
                        (int)cvtpk(p[8 * half + 2], p[8 * half + 3]),
                        (int)cvtpk(p[8 * half + 6], p[8 * half + 7]), false, false);
                    u32x4 wds;
                    wds[0] = (unsigned)r0[0]; wds[1] = (unsigned)r1[0];
                    wds[2] = (unsigned)r0[1]; wds[3] = (unsigned)r1[1];
                    bfr[qt][half] = __builtin_bit_cast(bf16x8, wds);
                }
            }
#pragma unroll
            for (int dt = 0; dt < 2; ++dt) {
                bf16x8 vf[2];
#pragma unroll
                for (int half = 0; half < 2; ++half)
                    vf[half] = *(const bf16x8*)&Vt[cur][dt * 32 + l31][(kvt * 2 + half) * 16 + h8 * 8];
#pragma unroll
                for (int qt = 0; qt < 2; ++qt)
#pragma unroll
                    for (int half = 0; half < 2; ++half)
                        o[dt][qt] = mfma32(vf[half], bfr[qt][half], o[dt][qt]);
            }
        }

        if (t + 1 < NT) {
            int nb = (t + 1) & 1;
            *(bf16x8*)&Ks[nb][kr][ksc * 16]     = kst0;
            *(bf16x8*)&Ks[nb][kr][ksc * 16 + 8] = kst1;
            u16x8 ua = __builtin_bit_cast(u16x8, vst0), ub = __builtin_bit_cast(u16x8, vst1);
#pragma unroll
            for (int j = 0; j < 8; ++j) {
                unsigned wd = (unsigned)ua[j] | ((unsigned)ub[j] << 16);
                *(unsigned*)&Vt[nb][vc * 8 + j][2 * vp] = wd;
            }
        }
    }

#pragma unroll
    for (int qt = 0; qt < 2; ++qt) {
        float lt = ls[qt] + __shfl_xor(ls[qt], 32);
        if (l < 32)
            lpart[((size_t)sp * 4 + h) * NE + q0 + wv * 64 + qt * 32 + l31] = lt;
    }

    float* Of = (float*)smem;
#pragma unroll
    for (int pass = 0; pass < 2; ++pass) {
        __syncthreads();
        if ((wv >> 1) == pass) {
#pragma unroll
            for (int dt = 0; dt < 2; ++dt)
#pragma unroll
                for (int qt = 0; qt < 2; ++qt)
#pragma unroll
                    for (int r = 0; r < 16; ++r) {
                        int qrel = (wv & 1) * 64 + qt * 32 + l31;
                        int d = dt * 32 + (r & 3) + 8 * (r >> 2) + 4 * h8;
                        Of[qrel * 68 + d] = o[dt][qt][r];
                    }
        }
        __syncthreads();
        {
            int rr = tid >> 1, hf = tid & 1;
            bf16_t* dst = &Opart[(size_t)sp * NE * 256 +
                                 (size_t)(q0 + pass * 128 + rr) * 256 + h * 64 + hf * 32];
#pragma unroll
            for (int i = 0; i < 4; ++i) {
                float4 va = *(float4*)&Of[rr * 68 + hf * 32 + i * 8];
                float4 vb = *(float4*)&Of[rr * 68 + hf * 32 + i * 8 + 4];
                bf16x8 ob;
                ob[0] = (bf16_t)va.x; ob[1] = (bf16_t)va.y;
                ob[2] = (bf16_t)va.z; ob[3] = (bf16_t)va.w;
                ob[4] = (bf16_t)vb.x; ob[5] = (bf16_t)vb.y;
                ob[6] = (bf16_t)vb.z; ob[7] = (bf16_t)vb.w;
                *(bf16x8*)&dst[i * 8] = ob;
            }
        }
    }
}

// ---------------------------------------------------------------------------
// LayerNorm over rows of 256: out = LN(x + y) * g + b
// XBF16/YBF16: inputs bf16. WRITE_F32/WRITE_BF16 select outputs.
// SCATTER: fused coalesced scatter via LDS transpose (thread t hits
// acc[dst*256+t], consecutive across the wave — R9's slow version was
// lane-strided).
// ---------------------------------------------------------------------------
template<int XBF16, int YBF16, int WRITE_F32, int WRITE_BF16, int SCATTER>
__global__ __launch_bounds__(256)
void ln_kernel(const void* __restrict__ xv, const void* __restrict__ yv,
               const float* __restrict__ g, const float* __restrict__ b,
               float* __restrict__ outf, bf16_t* __restrict__ outb,
               const int* __restrict__ ei, float* __restrict__ acc,
               float* __restrict__ cnt) {
    __shared__ float sl[SCATTER ? 4 : 1][SCATTER ? 256 : 1];
    int w = threadIdx.x >> 6;
    int row = blockIdx.x * 4 + w;
    int l = threadIdx.x & 63;
    float x0, x1, x2, x3, y0, y1, y2, y3;
    if (XBF16) {
        bf16x4 t = ((const bf16x4*)xv)[(long)row * 64 + l];
        x0 = (float)t[0]; x1 = (float)t[1]; x2 = (float)t[2]; x3 = (float)t[3];
    } else {
        float4 t = ((const float4*)xv)[(long)row * 64 + l];
        x0 = t.x; x1 = t.y; x2 = t.z; x3 = t.w;
    }
    if (YBF16) {
        bf16x4 t = ((const bf16x4*)yv)[(long)row * 64 + l];
        y0 = (float)t[0]; y1 = (float)t[1]; y2 = (float)t[2]; y3 = (float)t[3];
    } else {
        float4 t = ((const float4*)yv)[(long)row * 64 + l];
        y0 = t.x; y1 = t.y; y2 = t.z; y3 = t.w;
    }
    float a0 = x0 + y0, a1 = x1 + y1, a2 = x2 + y2, a3 = x3 + y3;

    float s = a0 + a1 + a2 + a3;
#pragma unroll
    for (int off = 1; off < 64; off <<= 1) s += __shfl_xor(s, off);
    float mu = s * (1.0f / 256.0f);

    float d0 = a0 - mu, d1 = a1 - mu, d2 = a2 - mu, d3 = a3 - mu;
    float q = d0 * d0 + d1 * d1 + d2 * d2 + d3 * d3;
#pragma unroll
    for (int off = 1; off < 64; off <<= 1) q += __shfl_xor(q, off);
    float rs = rsqrtf(q * (1.0f / 256.0f) + 1e-5f);

    float4 gg = ((const float4*)g)[l];
    float4 bb = ((const float4*)b)[l];
    float o0 = d0 * rs * gg.x + bb.x;
    float o1 = d1 * rs * gg.y + bb.y;
    float o2 = d2 * rs * gg.z + bb.z;
    float o3 = d3 * rs * gg.w + bb.w;
    if (WRITE_F32) {
        float4 ov; ov.x = o0; ov.y = o1; ov.z = o2; ov.w = o3;
        ((float4*)&outf[(long)row * 256])[l] = ov;
    }
    if (WRITE_BF16) {
        bf16x4 ob;
        ob[0] = (bf16_t)o0; ob[1] = (bf16_t)o1; ob[2] = (bf16_t)o2; ob[3] = (bf16_t)o3;
        ((bf16x4*)&outb[(long)row * 256])[l] = ob;
    }
    if (SCATTER) {
        sl[w][l * 4 + 0] = o0; sl[w][l * 4 + 1] = o1;
        sl[w][l * 4 + 2] = o2; sl[w][l * 4 + 3] = o3;
        __syncthreads();
        int t = threadIdx.x;
#pragma unroll
        for (int r = 0; r < 4; ++r) {
            int dst = ei[NE + blockIdx.x * 4 + r];
            atomicAdd(&acc[(long)dst * 256 + t], sl[r][t]);
        }
        if (t < 4) atomicAdd(&cnt[ei[NE + blockIdx.x * 4 + t]], 1.0f);
    }
}

// ---------------------------------------------------------------------------
extern "C" void kernel_launch(void* const* d_in, const int* in_sizes, int n_in,
                              void* d_out, int out_size, void* d_ws, size_t ws_size,
                              hipStream_t stream) {
    const float* node_features = (const float*)d_in[0];
    const float* edge_features = (const float*)d_in[1];
    const float* in_proj_w  = (const float*)d_in[2];
    const float* in_proj_b  = (const float*)d_in[3];
    const float* out_proj_w = (const float*)d_in[4];
    const float* out_proj_b = (const float*)d_in[5];
    const float* mlp_w1 = (const float*)d_in[6];
    const float* mlp_b1 = (const float*)d_in[7];
    const float* mlp_w2 = (const float*)d_in[8];
    const float* mlp_b2 = (const float*)d_in[9];
    const float* nu_w   = (const float*)d_in[10];
    const float* nu_b   = (const float*)d_in[11];
    const float* ln1_g  = (const float*)d_in[12];
    const float* ln1_b  = (const float*)d_in[13];
    const float* ln2_g  = (const float*)d_in[14];
    const float* ln2_b  = (const float*)d_in[15];
    const int*   edge_index = (const int*)d_in[16];

    char* ws = (char*)d_ws;
    size_t off = 0;
    auto alloc = [&](size_t bytes) {
        char* p = ws + off;
        off = (off + bytes + 255) & ~(size_t)255;
        return p;
    };
    // all linear — Opart now lives until out_proj (AMERGE), so no union
    bf16_t* ebf   = (bf16_t*)alloc(NE * HH * 2);
    bf16_t* bwq   = (bf16_t*)alloc(768 * 256 * 2);
    bf16_t* bwo   = (bf16_t*)alloc(256 * 256 * 2);
    bf16_t* bw1   = (bf16_t*)alloc(256 * 256 * 2);
    bf16_t* bw2   = (bf16_t*)alloc(256 * 256 * 2);
    bf16_t* bwn   = (bf16_t*)alloc(256 * 256 * 2);
    bf16_t* qkv   = (bf16_t*)alloc((size_t)NE * 768 * 2);
    float*  lpart = (float*)alloc((size_t)NSPLIT * 4 * NE * 4);
    float*  acc   = (float*)alloc((size_t)(NN * HH + NN) * 4);
    float*  cnt   = acc + (size_t)NN * HH;
    bf16_t* Opart = (bf16_t*)alloc((size_t)NSPLIT * NE * HH * 2);   // 16.8 MB
    bf16_t* attended = (bf16_t*)alloc((size_t)NE * HH * 2);
    bf16_t* e1b   = (bf16_t*)alloc((size_t)NE * HH * 2);
    bf16_t* hbuf  = (bf16_t*)alloc((size_t)NE * HH * 2);
    bf16_t* mlpout = (bf16_t*)alloc((size_t)NE * HH * 2);

    float* nout = (float*)d_out;
    float* eout = (float*)d_out + (size_t)NN * HH;

    convert_kernel<<<2048, 256, 0, stream>>>(edge_features, in_proj_w, out_proj_w,
                                             mlp_w1, mlp_w2, nu_w,
                                             ebf, bwq, bwo, bw1, bw2, bwn);

    // zero node accumulators (completes long before the fused LN2 scatter)
    hipMemsetAsync(acc, 0, (size_t)(NN * HH + NN) * 4, stream);

    // qkv = ebf @ in_proj_w^T + b -> bf16 [NE,768]; Q cols pre-scaled
    gemm_kernel<0, 1, 1, 0, 0><<<dim3(NE / 64, 768 / 64), 256, 0, stream>>>(
        ebf, bwq, in_proj_b, qkv, nullptr, nullptr, nullptr, NE, 768, 256);

    attn_kernel<<<dim3(128, NSPLIT), 256, 0, stream>>>(qkv, Opart, lpart);

    // attended = merge(Opart,lpart) @ out_proj_w^T + b -> bf16
    // (attn split-merge fused into A-staging; A re-read only 4x, L3-hot)
    gemm_kernel<0, 1, 0, 0, 1><<<dim3(NE / 64, 256 / 64), 256, 0, stream>>>(
        Opart, bwo, out_proj_b, attended, nullptr, nullptr, lpart, NE, 256, 256);

    // e1 = LN(edge_features + attended) -> e1b bf16 only
    ln_kernel<0, 1, 0, 1, 0><<<NE / 4, 256, 0, stream>>>(
        edge_features, attended, ln1_g, ln1_b, nullptr, e1b,
        nullptr, nullptr, nullptr);

    // h = relu(e1 @ w1^T + b1) -> bf16
    gemm_kernel<1, 1, 0, 0, 0><<<dim3(NE / 64, 256 / 64), 256, 0, stream>>>(
        e1b, bw1, mlp_b1, hbuf, nullptr, nullptr, nullptr, NE, 256, 256);

    // mlpout = h @ w2^T + b2 -> bf16 (read once by LN2)
    gemm_kernel<0, 1, 0, 0, 0><<<dim3(NE / 64, 256 / 64), 256, 0, stream>>>(
        hbuf, bw2, mlp_b2, mlpout, nullptr, nullptr, nullptr, NE, 256, 256);

    // e = LN(e1 + mlpout) -> d_out (second output) + fused coalesced scatter
    ln_kernel<1, 1, 1, 0, 1><<<NE / 4, 256, 0, stream>>>(
        e1b, mlpout, ln2_g, ln2_b, eout, nullptr,
        edge_index, acc, cnt);

    // n = node_features + relu((acc/cnt) @ nu_w^T + nu_b) -> d_out (first output)
    gemm_kernel<0, 2, 0, 1, 0><<<dim3(NN / 64, 256 / 64), 256, 0, stream>>>(
        acc, bwn, nu_b, nout, node_features, cnt, nullptr, NN, 256, 256);
}

// Round 14
// 132.698 us; speedup vs baseline: 1.2225x; 1.0350x over previous
//
#include <hip/hip_runtime.h>

typedef __bf16 bf16_t;
typedef __bf16 bf16x8 __attribute__((ext_vector_type(8)));
typedef __bf16 bf16x4 __attribute__((ext_vector_type(4)));
typedef unsigned short u16x8 __attribute__((ext_vector_type(8)));
typedef unsigned int u32x4 __attribute__((ext_vector_type(4)));
typedef float f32x4 __attribute__((ext_vector_type(4)));
typedef float f32x16 __attribute__((ext_vector_type(16)));
typedef int i32x2 __attribute__((ext_vector_type(2)));

#define NE 8192
#define NN 2048
#define HH 256
#define NSPLIT 4
// 0.125 * log2(e): folded into Q so P = exp2(S)
#define QSCALE 0.18033688011112042f

#if __has_builtin(__builtin_amdgcn_exp2f)
#define EXP2(x) __builtin_amdgcn_exp2f(x)
#else
#define EXP2(x) exp2f(x)
#endif

__device__ inline f32x4 mfma16(bf16x8 a, bf16x8 b, f32x4 c) {
    return __builtin_amdgcn_mfma_f32_16x16x32_bf16(a, b, c, 0, 0, 0);
}
__device__ inline f32x16 mfma32(bf16x8 a, bf16x8 b, f32x16 c) {
    return __builtin_amdgcn_mfma_f32_32x32x16_bf16(a, b, c, 0, 0, 0);
}
__device__ inline unsigned cvtpk(float lo, float hi) {
    unsigned r;
    asm("v_cvt_pk_bf16_f32 %0, %1, %2" : "=v"(r) : "v"(lo), "v"(hi));
    return r;
}
__device__ inline bf16x8 cvt8(float4 a, float4 b) {
    bf16x8 o;
    o[0] = (bf16_t)a.x; o[1] = (bf16_t)a.y; o[2] = (bf16_t)a.z; o[3] = (bf16_t)a.w;
    o[4] = (bf16_t)b.x; o[5] = (bf16_t)b.y; o[6] = (bf16_t)b.z; o[7] = (bf16_t)b.w;
    return o;
}
__device__ inline bf16x4 cvt4(float4 v) {
    bf16x4 o;
    o[0] = (bf16_t)v.x; o[1] = (bf16_t)v.y; o[2] = (bf16_t)v.z; o[3] = (bf16_t)v.w;
    return o;
}

// ---------------------------------------------------------------------------
// convert fp32 -> bf16: edge_features + 5 weight matrices (one pass), and
// zero the node accumulators (folds the hipMemsetAsync dispatch in here:
// acc+cnt = 526336 floats = 131584 float4 slots <= 524288 threads).
// ---------------------------------------------------------------------------
__global__ __launch_bounds__(256)
void convert_kernel(const float* __restrict__ ef, const float* __restrict__ wq,
                    const float* __restrict__ wo, const float* __restrict__ w1,
                    const float* __restrict__ w2, const float* __restrict__ wn,
                    bf16_t* __restrict__ ebf, bf16_t* __restrict__ bwq,
                    bf16_t* __restrict__ bwo, bf16_t* __restrict__ bw1,
                    bf16_t* __restrict__ bw2, bf16_t* __restrict__ bwn,
                    float* __restrict__ accz) {
    int i = blockIdx.x * 256 + threadIdx.x;   // 0 .. 524287
    ((bf16x4*)ebf)[i] = cvt4(((const float4*)ef)[i]);
    if (i < 49152) ((bf16x4*)bwq)[i] = cvt4(((const float4*)wq)[i]);
    if (i < 16384) {
        ((bf16x4*)bwo)[i] = cvt4(((const float4*)wo)[i]);
        ((bf16x4*)bw1)[i] = cvt4(((const float4*)w1)[i]);
        ((bf16x4*)bw2)[i] = cvt4(((const float4*)w2)[i]);
        ((bf16x4*)bwn)[i] = cvt4(((const float4*)wn)[i]);
    }
    if (i < (NN * HH + NN) / 4) {
        float4 z; z.x = 0.f; z.y = 0.f; z.z = 0.f; z.w = 0.f;
        ((float4*)accz)[i] = z;
    }
}

// ---------------------------------------------------------------------------
// Generic bf16 GEMM: C = act(A * B^T + bias)  [A: MxK, B: NxK row-major bf16]
// 64x64 tile, BK=64, 256 threads (4 waves, each a 32x32 quadrant)
// ADIV: A is fp32, each row scaled by 1/max(cnt[row],1) during staging.
// AMERGE: A is attention split-partials Opart [NSPLIT][M][256] bf16 + lprt
//   row-sums; staging computes sum_sp(Opart)/sum_sp(l) (h = k0>>6).
// ---------------------------------------------------------------------------
template<int ACT, int OUTKIND, int ADIV, int AMERGE>
__global__ __launch_bounds__(256)
void gemm_kernel(const void* __restrict__ Av, const bf16_t* __restrict__ B,
                 const float* __restrict__ bias, void* __restrict__ out,
                 const float* __restrict__ resid, const float* __restrict__ cntp,
                 const float* __restrict__ lprt, int M, int N, int K) {
    __shared__ bf16_t As[64][72];
    __shared__ bf16_t Bs[64][72];
    int tid = threadIdx.x;
    int w = tid >> 6, l = tid & 63, hi = l >> 4, c15 = l & 15;
    int wr = w >> 1, wc = w & 1;
    int brow = blockIdx.x * 64, bcol = blockIdx.y * 64;
    int r = tid >> 2, s = tid & 3;

    f32x4 acc[2][2] = {};

    for (int k0 = 0; k0 < K; k0 += 64) {
        __syncthreads();
        if (ADIV) {
            const float* Af = (const float*)Av;
            const float* p = &Af[(long)(brow + r) * K + k0 + s * 16];
            float4 f0 = *(const float4*)p,       f1 = *(const float4*)(p + 4);
            float4 f2 = *(const float4*)(p + 8), f3 = *(const float4*)(p + 12);
            float rc = 1.0f / fmaxf(cntp[brow + r], 1.0f);
            f0.x *= rc; f0.y *= rc; f0.z *= rc; f0.w *= rc;
            f1.x *= rc; f1.y *= rc; f1.z *= rc; f1.w *= rc;
            f2.x *= rc; f2.y *= rc; f2.z *= rc; f2.w *= rc;
            f3.x *= rc; f3.y *= rc; f3.z *= rc; f3.w *= rc;
            *(bf16x8*)&As[r][s * 16]     = cvt8(f0, f1);
            *(bf16x8*)&As[r][s * 16 + 8] = cvt8(f2, f3);
        } else if (AMERGE) {
            const bf16_t* Am = (const bf16_t*)Av;
            int q = brow + r;
            int hh = k0 >> 6;                 // head index, constant per k-step
            float lsum = 0.f;
            float sum[16] = {};
#pragma unroll
            for (int sp = 0; sp < NSPLIT; ++sp) {
                lsum += lprt[((size_t)sp * 4 + hh) * M + q];
                const bf16_t* src = &Am[((size_t)sp * M + q) * 256 + k0 + s * 16];
                bf16x8 va = *(const bf16x8*)src;
                bf16x8 vb = *(const bf16x8*)(src + 8);
#pragma unroll
                for (int j = 0; j < 8; ++j) {
                    sum[j]     += (float)va[j];
                    sum[8 + j] += (float)vb[j];
                }
            }
            float rl = 1.0f / lsum;
            bf16x8 o0, o1;
#pragma unroll
            for (int j = 0; j < 8; ++j) {
                o0[j] = (bf16_t)(sum[j] * rl);
                o1[j] = (bf16_t)(sum[8 + j] * rl);
            }
            *(bf16x8*)&As[r][s * 16]     = o0;
            *(bf16x8*)&As[r][s * 16 + 8] = o1;
        } else {
            const bf16_t* Ab = (const bf16_t*)Av;
            *(bf16x8*)&As[r][s * 16]     = *(const bf16x8*)&Ab[(long)(brow + r) * K + k0 + s * 16];
            *(bf16x8*)&As[r][s * 16 + 8] = *(const bf16x8*)&Ab[(long)(brow + r) * K + k0 + s * 16 + 8];
        }
        *(bf16x8*)&Bs[r][s * 16]     = *(const bf16x8*)&B[(long)(bcol + r) * K + k0 + s * 16];
        *(bf16x8*)&Bs[r][s * 16 + 8] = *(const bf16x8*)&B[(long)(bcol + r) * K + k0 + s * 16 + 8];
        __syncthreads();
#pragma unroll
        for (int c = 0; c < 2; ++c) {
            bf16x8 af0 = *(const bf16x8*)&As[wr * 32 + c15][c * 32 + hi * 8];
            bf16x8 af1 = *(const bf16x8*)&As[wr * 32 + 16 + c15][c * 32 + hi * 8];
            bf16x8 bf0 = *(const bf16x8*)&Bs[wc * 32 + c15][c * 32 + hi * 8];
            bf16x8 bf1 = *(const bf16x8*)&Bs[wc * 32 + 16 + c15][c * 32 + hi * 8];
            acc[0][0] = mfma16(af0, bf0, acc[0][0]);
            acc[0][1] = mfma16(af0, bf1, acc[0][1]);
            acc[1][0] = mfma16(af1, bf0, acc[1][0]);
            acc[1][1] = mfma16(af1, bf1, acc[1][1]);
        }
    }

#pragma unroll
    for (int i = 0; i < 2; ++i)
#pragma unroll
        for (int j = 0; j < 2; ++j)
#pragma unroll
            for (int rg = 0; rg < 4; ++rg) {
                int row = brow + wr * 32 + i * 16 + hi * 4 + rg;
                int col = bcol + wc * 32 + j * 16 + c15;
                float v = acc[i][j][rg] + bias[col];
                if (ACT) v = fmaxf(v, 0.0f);
                if (OUTKIND == 0) {
                    ((float*)out)[(long)row * N + col] = v;
                } else if (OUTKIND == 1) {
                    ((bf16_t*)out)[(long)row * N + col] = (bf16_t)v;
                } else {
                    ((float*)out)[(long)row * N + col] =
                        resid[(long)row * N + col] + fmaxf(v, 0.0f);
                }
            }
}

// ---------------------------------------------------------------------------
// qkv GEMM, 128x64 tile, 512 threads (8 waves): staging elems/thread 32->24
// and 2x MFMA per barrier-pair vs the 64x64 tile — better amortization for
// the K=256 (4 k-step) shape. Q cols (<256) pre-scaled by QSCALE.
// grid = (NE/128, 768/64) = 768 blocks = 3 blocks/CU = 24 waves/CU.
// ---------------------------------------------------------------------------
__global__ __launch_bounds__(512)
void gemm_qkv_kernel(const bf16_t* __restrict__ A, const bf16_t* __restrict__ B,
                     const float* __restrict__ bias, bf16_t* __restrict__ out) {
    __shared__ bf16_t As[128][72];
    __shared__ bf16_t Bs[64][72];
    const int K = 256, N = 768;
    int tid = threadIdx.x;
    int w = tid >> 6, l = tid & 63, hi = l >> 4, c15 = l & 15;
    int wr = w >> 1, wc = w & 1;          // wr 0..3 (128 rows), wc 0..1 (64 cols)
    int brow = blockIdx.x * 128, bcol = blockIdx.y * 64;
    int r = tid >> 2, s = tid & 3;        // A staging: 128 rows x 4 chunks
    int rb = tid >> 3, sb = tid & 7;      // B staging: 64 rows x 8 chunks

    f32x4 acc[2][2] = {};

    for (int k0 = 0; k0 < K; k0 += 64) {
        __syncthreads();
        *(bf16x8*)&As[r][s * 16]     = *(const bf16x8*)&A[(long)(brow + r) * K + k0 + s * 16];
        *(bf16x8*)&As[r][s * 16 + 8] = *(const bf16x8*)&A[(long)(brow + r) * K + k0 + s * 16 + 8];
        *(bf16x8*)&Bs[rb][sb * 8]    = *(const bf16x8*)&B[(long)(bcol + rb) * K + k0 + sb * 8];
        __syncthreads();
#pragma unroll
        for (int c = 0; c < 2; ++c) {
            bf16x8 af0 = *(const bf16x8*)&As[wr * 32 + c15][c * 32 + hi * 8];
            bf16x8 af1 = *(const bf16x8*)&As[wr * 32 + 16 + c15][c * 32 + hi * 8];
            bf16x8 bf0 = *(const bf16x8*)&Bs[wc * 32 + c15][c * 32 + hi * 8];
            bf16x8 bf1 = *(const bf16x8*)&Bs[wc * 32 + 16 + c15][c * 32 + hi * 8];
            acc[0][0] = mfma16(af0, bf0, acc[0][0]);
            acc[0][1] = mfma16(af0, bf1, acc[0][1]);
            acc[1][0] = mfma16(af1, bf0, acc[1][0]);
            acc[1][1] = mfma16(af1, bf1, acc[1][1]);
        }
    }

    float sc = (bcol < 256) ? QSCALE : 1.0f;
#pragma unroll
    for (int i = 0; i < 2; ++i)
#pragma unroll
        for (int j = 0; j < 2; ++j)
#pragma unroll
            for (int rg = 0; rg < 4; ++rg) {
                int row = brow + wr * 32 + i * 16 + hi * 4 + rg;
                int col = bcol + wc * 32 + j * 16 + c15;
                float v = (acc[i][j][rg] + bias[col]) * sc;
                out[(long)row * N + col] = (bf16_t)v;
            }
}

// ---------------------------------------------------------------------------
// Flash attention, 32x32x16 MFMA, swapped QK^T (S^T = K Q^T): softmax is
// lane-local, P feeds PV's B-operand via cvt_pk + permlane32_swap (no LDS).
// Q pre-scaled by 0.125*log2e so P = exp2(S).
// Block: 256 thr = 4 waves, each wave 64 q-rows (2 qt sub-tiles) -> q-block 256.
// grid = dim3(128, NSPLIT=4) = 512 blocks = exactly 2 blocks/CU — matches the
// register-file residency cap. NO s_setprio (R6: -9 us). 1 barrier/tile.
// ~921 TF effective — at the 2-barrier-structure plateau (MFMA floor 28.8 us).
// ---------------------------------------------------------------------------
__global__ __launch_bounds__(256, 2)
void attn_kernel(const bf16_t* __restrict__ qkv, bf16_t* __restrict__ Opart,
                 float* __restrict__ lpart) {
    __shared__ char smem[36864];
    bf16_t (*Ks)[64][72] = (bf16_t (*)[64][72])smem;             // [buf][kv][d]
    bf16_t (*Vt)[64][72] = (bf16_t (*)[64][72])(smem + 18432);   // [buf][d][kv]

    int h = blockIdx.x & 3, qb = blockIdx.x >> 2, sp = blockIdx.y;
    int q0 = qb * 256;
    int tid = threadIdx.x;
    int wv = tid >> 6, l = tid & 63, l31 = l & 31, h8 = l >> 5;

    bf16x8 qf[2][4];
#pragma unroll
    for (int qt = 0; qt < 2; ++qt)
#pragma unroll
        for (int dc = 0; dc < 4; ++dc)
            qf[qt][dc] = *(const bf16x8*)&qkv[
                (size_t)(q0 + wv * 64 + qt * 32 + l31) * 768 + h * 64 + dc * 16 + h8 * 8];

    f32x16 o[2][2];
#pragma unroll
    for (int a = 0; a < 2; ++a)
#pragma unroll
        for (int b = 0; b < 2; ++b)
#pragma unroll
            for (int r = 0; r < 16; ++r) o[a][b][r] = 0.f;
    float ls[2] = {0.f, 0.f};

    // persistent zero C-operand for the S MFMA chain
    f32x16 z16;
#pragma unroll
    for (int r = 0; r < 16; ++r) z16[r] = 0.f;

    int kr = tid >> 2, ksc = tid & 3;
    int vp = tid & 31, vc = tid >> 5;
    int kv0 = sp * (NE / NSPLIT);
    const int NT = (NE / NSPLIT) / 64;

    bf16x8 kst0, kst1, vst0, vst1;
    {
        const bf16_t* ksrc = &qkv[(size_t)(kv0 + kr) * 768 + 256 + h * 64 + ksc * 16];
        kst0 = *(const bf16x8*)ksrc; kst1 = *(const bf16x8*)(ksrc + 8);
        const bf16_t* vsrc = &qkv[(size_t)(kv0 + 2 * vp) * 768 + 512 + h * 64 + vc * 8];
        vst0 = *(const bf16x8*)vsrc; vst1 = *(const bf16x8*)(vsrc + 768);
    }
    {
        *(bf16x8*)&Ks[0][kr][ksc * 16]     = kst0;
        *(bf16x8*)&Ks[0][kr][ksc * 16 + 8] = kst1;
        u16x8 ua = __builtin_bit_cast(u16x8, vst0), ub = __builtin_bit_cast(u16x8, vst1);
#pragma unroll
        for (int j = 0; j < 8; ++j) {
            unsigned wd = (unsigned)ua[j] | ((unsigned)ub[j] << 16);
            *(unsigned*)&Vt[0][vc * 8 + j][2 * vp] = wd;
        }
    }

    for (int t = 0; t < NT; ++t) {
        int cur = t & 1;
        __syncthreads();
        if (t + 1 < NT) {
            int kt = kv0 + (t + 1) * 64;
            const bf16_t* ksrc = &qkv[(size_t)(kt + kr) * 768 + 256 + h * 64 + ksc * 16];
            kst0 = *(const bf16x8*)ksrc; kst1 = *(const bf16x8*)(ksrc + 8);
            const bf16_t* vsrc = &qkv[(size_t)(kt + 2 * vp) * 768 + 512 + h * 64 + vc * 8];
            vst0 = *(const bf16x8*)vsrc; vst1 = *(const bf16x8*)(vsrc + 768);
        }

#pragma unroll
        for (int kvt = 0; kvt < 2; ++kvt) {
            bf16x8 kf[4];
#pragma unroll
            for (int dc = 0; dc < 4; ++dc)
                kf[dc] = *(const bf16x8*)&Ks[cur][kvt * 32 + l31][dc * 16 + h8 * 8];
            f32x16 s[2];
#pragma unroll
            for (int qt = 0; qt < 2; ++qt) {
                s[qt] = mfma32(kf[0], qf[qt][0], z16);
#pragma unroll
                for (int dc = 1; dc < 4; ++dc)
                    s[qt] = mfma32(kf[dc], qf[qt][dc], s[qt]);
            }
            bf16x8 bfr[2][2];
#pragma unroll
            for (int qt = 0; qt < 2; ++qt) {
                float p[16];
#pragma unroll
                for (int r = 0; r < 16; ++r) { p[r] = EXP2(s[qt][r]); ls[qt] += p[r]; }
#pragma unroll
                for (int half = 0; half < 2; ++half) {
                    i32x2 r0 = __builtin_amdgcn_permlane32_swap(
                        (int)cvtpk(p[8 * half + 0], p[8 * half + 1]),
                        (int)cvtpk(p[8 * half + 4], p[8 * half + 5]), false, false);
                    i32x2 r1 = __builtin_amdgcn_permlane32_swap(
                        (int)cvtpk(p[8 * half + 2], p[8 * half + 3]),
                        (int)cvtpk(p[8 * half + 6], p[8 * half + 7]), false, false);
                    u32x4 wds;
                    wds[0] = (unsigned)r0[0]; wds[1] = (unsigned)r1[0];
                    wds[2] = (unsigned)r0[1]; wds[3] = (unsigned)r1[1];
                    bfr[qt][half] = __builtin_bit_cast(bf16x8, wds);
                }
            }
#pragma unroll
            for (int dt = 0; dt < 2; ++dt) {
                bf16x8 vf[2];
#pragma unroll
                for (int half = 0; half < 2; ++half)
                    vf[half] = *(const bf16x8*)&Vt[cur][dt * 32 + l31][(kvt * 2 + half) * 16 + h8 * 8];
#pragma unroll
                for (int qt = 0; qt < 2; ++qt)
#pragma unroll
                    for (int half = 0; half < 2; ++half)
                        o[dt][qt] = mfma32(vf[half], bfr[qt][half], o[dt][qt]);
            }
        }

        if (t + 1 < NT) {
            int nb = (t + 1) & 1;
            *(bf16x8*)&Ks[nb][kr][ksc * 16]     = kst0;
            *(bf16x8*)&Ks[nb][kr][ksc * 16 + 8] = kst1;
            u16x8 ua = __builtin_bit_cast(u16x8, vst0), ub = __builtin_bit_cast(u16x8, vst1);
#pragma unroll
            for (int j = 0; j < 8; ++j) {
                unsigned wd = (unsigned)ua[j] | ((unsigned)ub[j] << 16);
                *(unsigned*)&Vt[nb][vc * 8 + j][2 * vp] = wd;
            }
        }
    }

#pragma unroll
    for (int qt = 0; qt < 2; ++qt) {
        float lt = ls[qt] + __shfl_xor(ls[qt], 32);
        if (l < 32)
            lpart[((size_t)sp * 4 + h) * NE + q0 + wv * 64 + qt * 32 + l31] = lt;
    }

    float* Of = (float*)smem;
#pragma unroll
    for (int pass = 0; pass < 2; ++pass) {
        __syncthreads();
        if ((wv >> 1) == pass) {
#pragma unroll
            for (int dt = 0; dt < 2; ++dt)
#pragma unroll
                for (int qt = 0; qt < 2; ++qt)
#pragma unroll
                    for (int r = 0; r < 16; ++r) {
                        int qrel = (wv & 1) * 64 + qt * 32 + l31;
                        int d = dt * 32 + (r & 3) + 8 * (r >> 2) + 4 * h8;
                        Of[qrel * 68 + d] = o[dt][qt][r];
                    }
        }
        __syncthreads();
        {
            int rr = tid >> 1, hf = tid & 1;
            bf16_t* dst = &Opart[(size_t)sp * NE * 256 +
                                 (size_t)(q0 + pass * 128 + rr) * 256 + h * 64 + hf * 32];
#pragma unroll
            for (int i = 0; i < 4; ++i) {
                float4 va = *(float4*)&Of[rr * 68 + hf * 32 + i * 8];
                float4 vb = *(float4*)&Of[rr * 68 + hf * 32 + i * 8 + 4];
                bf16x8 ob;
                ob[0] = (bf16_t)va.x; ob[1] = (bf16_t)va.y;
                ob[2] = (bf16_t)va.z; ob[3] = (bf16_t)va.w;
                ob[4] = (bf16_t)vb.x; ob[5] = (bf16_t)vb.y;
                ob[6] = (bf16_t)vb.z; ob[7] = (bf16_t)vb.w;
                *(bf16x8*)&dst[i * 8] = ob;
            }
        }
    }
}

// ---------------------------------------------------------------------------
// LayerNorm over rows of 256: out = LN(x + y) * g + b
// XBF16/YBF16: inputs bf16. WRITE_F32/WRITE_BF16 select outputs.
// SCATTER: fused coalesced scatter via LDS transpose (thread t hits
// acc[dst*256+t], consecutive across the wave).
// ---------------------------------------------------------------------------
template<int XBF16, int YBF16, int WRITE_F32, int WRITE_BF16, int SCATTER>
__global__ __launch_bounds__(256)
void ln_kernel(const void* __restrict__ xv, const void* __restrict__ yv,
               const float* __restrict__ g, const float* __restrict__ b,
               float* __restrict__ outf, bf16_t* __restrict__ outb,
               const int* __restrict__ ei, float* __restrict__ acc,
               float* __restrict__ cnt) {
    __shared__ float sl[SCATTER ? 4 : 1][SCATTER ? 256 : 1];
    int w = threadIdx.x >> 6;
    int row = blockIdx.x * 4 + w;
    int l = threadIdx.x & 63;
    float x0, x1, x2, x3, y0, y1, y2, y3;
    if (XBF16) {
        bf16x4 t = ((const bf16x4*)xv)[(long)row * 64 + l];
        x0 = (float)t[0]; x1 = (float)t[1]; x2 = (float)t[2]; x3 = (float)t[3];
    } else {
        float4 t = ((const float4*)xv)[(long)row * 64 + l];
        x0 = t.x; x1 = t.y; x2 = t.z; x3 = t.w;
    }
    if (YBF16) {
        bf16x4 t = ((const bf16x4*)yv)[(long)row * 64 + l];
        y0 = (float)t[0]; y1 = (float)t[1]; y2 = (float)t[2]; y3 = (float)t[3];
    } else {
        float4 t = ((const float4*)yv)[(long)row * 64 + l];
        y0 = t.x; y1 = t.y; y2 = t.z; y3 = t.w;
    }
    float a0 = x0 + y0, a1 = x1 + y1, a2 = x2 + y2, a3 = x3 + y3;

    float s = a0 + a1 + a2 + a3;
#pragma unroll
    for (int off = 1; off < 64; off <<= 1) s += __shfl_xor(s, off);
    float mu = s * (1.0f / 256.0f);

    float d0 = a0 - mu, d1 = a1 - mu, d2 = a2 - mu, d3 = a3 - mu;
    float q = d0 * d0 + d1 * d1 + d2 * d2 + d3 * d3;
#pragma unroll
    for (int off = 1; off < 64; off <<= 1) q += __shfl_xor(q, off);
    float rs = rsqrtf(q * (1.0f / 256.0f) + 1e-5f);

    float4 gg = ((const float4*)g)[l];
    float4 bb = ((const float4*)b)[l];
    float o0 = d0 * rs * gg.x + bb.x;
    float o1 = d1 * rs * gg.y + bb.y;
    float o2 = d2 * rs * gg.z + bb.z;
    float o3 = d3 * rs * gg.w + bb.w;
    if (WRITE_F32) {
        float4 ov; ov.x = o0; ov.y = o1; ov.z = o2; ov.w = o3;
        ((float4*)&outf[(long)row * 256])[l] = ov;
    }
    if (WRITE_BF16) {
        bf16x4 ob;
        ob[0] = (bf16_t)o0; ob[1] = (bf16_t)o1; ob[2] = (bf16_t)o2; ob[3] = (bf16_t)o3;
        ((bf16x4*)&outb[(long)row * 256])[l] = ob;
    }
    if (SCATTER) {
        sl[w][l * 4 + 0] = o0; sl[w][l * 4 + 1] = o1;
        sl[w][l * 4 + 2] = o2; sl[w][l * 4 + 3] = o3;
        __syncthreads();
        int t = threadIdx.x;
#pragma unroll
        for (int r = 0; r < 4; ++r) {
            int dst = ei[NE + blockIdx.x * 4 + r];
            atomicAdd(&acc[(long)dst * 256 + t], sl[r][t]);
        }
        if (t < 4) atomicAdd(&cnt[ei[NE + blockIdx.x * 4 + t]], 1.0f);
    }
}

// ---------------------------------------------------------------------------
extern "C" void kernel_launch(void* const* d_in, const int* in_sizes, int n_in,
                              void* d_out, int out_size, void* d_ws, size_t ws_size,
                              hipStream_t stream) {
    const float* node_features = (const float*)d_in[0];
    const float* edge_features = (const float*)d_in[1];
    const float* in_proj_w  = (const float*)d_in[2];
    const float* in_proj_b  = (const float*)d_in[3];
    const float* out_proj_w = (const float*)d_in[4];
    const float* out_proj_b = (const float*)d_in[5];
    const float* mlp_w1 = (const float*)d_in[6];
    const float* mlp_b1 = (const float*)d_in[7];
    const float* mlp_w2 = (const float*)d_in[8];
    const float* mlp_b2 = (const float*)d_in[9];
    const float* nu_w   = (const float*)d_in[10];
    const float* nu_b   = (const float*)d_in[11];
    const float* ln1_g  = (const float*)d_in[12];
    const float* ln1_b  = (const float*)d_in[13];
    const float* ln2_g  = (const float*)d_in[14];
    const float* ln2_b  = (const float*)d_in[15];
    const int*   edge_index = (const int*)d_in[16];

    char* ws = (char*)d_ws;
    size_t off = 0;
    auto alloc = [&](size_t bytes) {
        char* p = ws + off;
        off = (off + bytes + 255) & ~(size_t)255;
        return p;
    };
    bf16_t* ebf   = (bf16_t*)alloc(NE * HH * 2);
    bf16_t* bwq   = (bf16_t*)alloc(768 * 256 * 2);
    bf16_t* bwo   = (bf16_t*)alloc(256 * 256 * 2);
    bf16_t* bw1   = (bf16_t*)alloc(256 * 256 * 2);
    bf16_t* bw2   = (bf16_t*)alloc(256 * 256 * 2);
    bf16_t* bwn   = (bf16_t*)alloc(256 * 256 * 2);
    bf16_t* qkv   = (bf16_t*)alloc((size_t)NE * 768 * 2);
    float*  lpart = (float*)alloc((size_t)NSPLIT * 4 * NE * 4);
    float*  acc   = (float*)alloc((size_t)(NN * HH + NN) * 4);
    float*  cnt   = acc + (size_t)NN * HH;
    bf16_t* Opart = (bf16_t*)alloc((size_t)NSPLIT * NE * HH * 2);   // 16.8 MB
    bf16_t* attended = (bf16_t*)alloc((size_t)NE * HH * 2);
    bf16_t* e1b   = (bf16_t*)alloc((size_t)NE * HH * 2);
    bf16_t* hbuf  = (bf16_t*)alloc((size_t)NE * HH * 2);
    bf16_t* mlpout = (bf16_t*)alloc((size_t)NE * HH * 2);

    float* nout = (float*)d_out;
    float* eout = (float*)d_out + (size_t)NN * HH;

    // convert + acc/cnt zeroing (memset dispatch folded in)
    convert_kernel<<<2048, 256, 0, stream>>>(edge_features, in_proj_w, out_proj_w,
                                             mlp_w1, mlp_w2, nu_w,
                                             ebf, bwq, bwo, bw1, bw2, bwn, acc);

    // qkv = ebf @ in_proj_w^T + b -> bf16 [NE,768]; Q cols pre-scaled
    // 128x64-tile 512-thread variant (better staging/barrier amortization)
    gemm_qkv_kernel<<<dim3(NE / 128, 768 / 64), 512, 0, stream>>>(
        ebf, bwq, in_proj_b, qkv);

    attn_kernel<<<dim3(128, NSPLIT), 256, 0, stream>>>(qkv, Opart, lpart);

    // attended = merge(Opart,lpart) @ out_proj_w^T + b -> bf16
    gemm_kernel<0, 1, 0, 1><<<dim3(NE / 64, 256 / 64), 256, 0, stream>>>(
        Opart, bwo, out_proj_b, attended, nullptr, nullptr, lpart, NE, 256, 256);

    // e1 = LN(edge_features + attended) -> e1b bf16 only
    ln_kernel<0, 1, 0, 1, 0><<<NE / 4, 256, 0, stream>>>(
        edge_features, attended, ln1_g, ln1_b, nullptr, e1b,
        nullptr, nullptr, nullptr);

    // h = relu(e1 @ w1^T + b1) -> bf16
    gemm_kernel<1, 1, 0, 0><<<dim3(NE / 64, 256 / 64), 256, 0, stream>>>(
        e1b, bw1, mlp_b1, hbuf, nullptr, nullptr, nullptr, NE, 256, 256);

    // mlpout = h @ w2^T + b2 -> bf16 (read once by LN2)
    gemm_kernel<0, 1, 0, 0><<<dim3(NE / 64, 256 / 64), 256, 0, stream>>>(
        hbuf, bw2, mlp_b2, mlpout, nullptr, nullptr, nullptr, NE, 256, 256);

    // e = LN(e1 + mlpout) -> d_out (second output) + fused coalesced scatter
    ln_kernel<1, 1, 1, 0, 1><<<NE / 4, 256, 0, stream>>>(
        e1b, mlpout, ln2_g, ln2_b, eout, nullptr,
        edge_index, acc, cnt);

    // n = node_features + relu((acc/cnt) @ nu_w^T + nu_b) -> d_out (first output)
    gemm_kernel<0, 2, 1, 0><<<dim3(NN / 64, 256 / 64), 256, 0, stream>>>(
        acc, bwn, nu_b, nout, node_features, cnt, nullptr, NN, 256, 256);
}